// Round 3
// baseline (623.704 us; speedup 1.0000x reference)
//
#include <hip/hip_runtime.h>
#include <hip/hip_bf16.h>
#include <math.h>

typedef __attribute__((ext_vector_type(8))) short short8;
typedef __attribute__((ext_vector_type(4))) float floatx4;

// ---------------------------------------------------------------- helpers
__device__ __forceinline__ void load_lds16(const void* g, void* l) {
  __builtin_amdgcn_global_load_lds(
      (__attribute__((address_space(1))) void*)(g),
      (__attribute__((address_space(3))) void*)(l), 16, 0, 0);
}

#define MFMA16x16x32(a, b, c) __builtin_amdgcn_mfma_f32_16x16x32_bf16((a), (b), (c), 0, 0, 0)
#define BARRIER() __builtin_amdgcn_s_barrier()
#define WAIT_LGKM0() asm volatile("s_waitcnt lgkmcnt(0)" ::: "memory")
#define WAIT_VM4() asm volatile("s_waitcnt vmcnt(4)" ::: "memory")
#define WAIT_VM0() asm volatile("s_waitcnt vmcnt(0)" ::: "memory")
#define SCHED_FENCE() __builtin_amdgcn_sched_barrier(0)

__device__ __forceinline__ float to_f(float x) { return x; }
__device__ __forceinline__ float to_f(__hip_bfloat16 x) { return __bfloat162float(x); }
__device__ __forceinline__ void st_val(float* p, float v) { *p = v; }
__device__ __forceinline__ void st_val(__hip_bfloat16* p, float v) { *p = __float2bfloat16(v); }

// ---------------------------------------------------------------- fp32 -> bf16 elementwise (src)
__global__ __launch_bounds__(256) void cvt_f32_bf16(const float4* __restrict__ in,
                                                    ushort* __restrict__ out) {
  int i = blockIdx.x * 256 + threadIdx.x;
  float4 v = in[i];
  ushort4 o;
  __hip_bfloat16 b0 = __float2bfloat16(v.x);
  __hip_bfloat16 b1 = __float2bfloat16(v.y);
  __hip_bfloat16 b2 = __float2bfloat16(v.z);
  __hip_bfloat16 b3 = __float2bfloat16(v.w);
  o.x = *(ushort*)&b0; o.y = *(ushort*)&b1; o.z = *(ushort*)&b2; o.w = *(ushort*)&b3;
  *(ushort4*)(out + 4 * i) = o;
}

// ---------------------------------------------------------------- concat 3 bias vectors (512 each)
__global__ void concat3(const float* __restrict__ a, const float* __restrict__ b,
                        const float* __restrict__ c, float* __restrict__ o) {
  int i = blockIdx.x * 256 + threadIdx.x;  // 0..1535
  o[i] = i < 512 ? a[i] : (i < 1024 ? b[i - 512] : c[i - 1024]);
}

// ---------------------------------------------------------------- fp32 weights -> bf16 transposed
__global__ void transpose_cvt(const float* __restrict__ in,
                              __hip_bfloat16* __restrict__ out, int R, int C) {
  __shared__ __hip_bfloat16 tile[32][33];
  int bx = blockIdx.x * 32, by = blockIdx.y * 32;
  int tx = threadIdx.x, ty = threadIdx.y;  // (32,8)
  for (int i = ty; i < 32; i += 8)
    tile[i][tx] = __float2bfloat16(in[(size_t)(by + i) * C + bx + tx]);
  __syncthreads();
  for (int i = ty; i < 32; i += 8) out[(size_t)(bx + i) * R + by + tx] = tile[tx][i];
}

// ---------------------------------------------------------------- GEMM: C[M,N] = A[M,K] @ BT[N,K]^T + bias, opt GELU
// 256x256 tile, BK=64, 8 waves (2M x 4N), per-wave 128x64 output (acc[8][4]).
// 8-phase schedule (T3+T4), counted vmcnt (never 0 mid-loop).
// LDS swizzle: within each 128-B row, 16-B chunk c holds global chunk c ^ (row&7).
//   - stage side: linear global_load_lds dest; per-lane GLOBAL source chunk
//     (l&7) ^ ((l>>3)&7)  (rows +8 keep row&7 -> one colb serves both chunks)
//   - read side: chunk' = (quad + 4*kk) ^ (m&7)  -> each quarter-wave hits all
//     8 chunks 2-per-chunk = 2-way = conflict-free (fixes round-2's 3.5M conflicts)
// LDS: A[2 dbuf][2 half][128 rows][64 kk] = 64 KB @0; B same @65536. Total 128 KB.
__global__ __launch_bounds__(512) void gemm256(
    const __hip_bfloat16* __restrict__ A,
    const __hip_bfloat16* __restrict__ BT,
    const float* __restrict__ bias,
    __hip_bfloat16* __restrict__ C,
    int M, int N, int K, int act, int tiles_x) {
  (void)M;
  __shared__ __align__(16) short8 smv[8192];  // 128 KB
  char* smc = (char*)smv;
  const int tid = threadIdx.x;
  const int wave = tid >> 6, lane = tid & 63;
  const int quad = lane >> 4, m = lane & 15;
  const int wmi = wave >> 2, wni = wave & 3;
  // bijective XCD-chunked swizzle (grid % 8 == 0 for all call sites)
  const int nwg = gridDim.x;
  const int wg = (blockIdx.x & 7) * (nwg >> 3) + (blockIdx.x >> 3);
  const int row0 = (wg / tiles_x) * 256;
  const int col0 = (wg % tiles_x) * 256;
  const int nt = K >> 6;

  // ---- staging source addressing (pre-swizzled chunk) ----
  const int colb = (((lane & 7) ^ ((lane >> 3) & 7)) << 4);
  const int rbase = wave * 16 + (lane >> 3);  // rows of chunk r=0; r=1 adds 8
  const char* pA0 = (const char*)(A + (size_t)(row0 + rbase) * K) + colb;
  const char* pA1 = (const char*)(A + (size_t)(row0 + rbase + 8) * K) + colb;
  const char* pA2 = (const char*)(A + (size_t)(row0 + 128 + rbase) * K) + colb;
  const char* pA3 = (const char*)(A + (size_t)(row0 + 128 + rbase + 8) * K) + colb;
  const char* pB0 = (const char*)(BT + (size_t)(col0 + rbase) * K) + colb;
  const char* pB1 = (const char*)(BT + (size_t)(col0 + rbase + 8) * K) + colb;
  const char* pB2 = (const char*)(BT + (size_t)(col0 + 128 + rbase) * K) + colb;
  const char* pB3 = (const char*)(BT + (size_t)(col0 + 128 + rbase + 8) * K) + colb;
  const int c0 = wave * 2048;        // LDS chunk r=0 (wave-uniform)
  const int c1 = wave * 2048 + 1024; // LDS chunk r=1

#define STAGE_A_H0(d)                          \
  do {                                         \
    load_lds16(pA0, smc + (d) + c0);           \
    load_lds16(pA1, smc + (d) + c1);           \
    pA0 += 128; pA1 += 128;                    \
  } while (0)
#define STAGE_A_H1(d)                          \
  do {                                         \
    load_lds16(pA2, smc + (d) + 16384 + c0);   \
    load_lds16(pA3, smc + (d) + 16384 + c1);   \
    pA2 += 128; pA3 += 128;                    \
  } while (0)
#define STAGE_B_H0(d)                              \
  do {                                             \
    load_lds16(pB0, smc + 65536 + (d) + c0);       \
    load_lds16(pB1, smc + 65536 + (d) + c1);       \
    pB0 += 128; pB1 += 128;                        \
  } while (0)
#define STAGE_B_H1(d)                                  \
  do {                                                 \
    load_lds16(pB2, smc + 65536 + (d) + 16384 + c0);   \
    load_lds16(pB3, smc + 65536 + (d) + 16384 + c1);   \
    pB2 += 128; pB3 += 128;                            \
  } while (0)

  // prologue: tile0 all 4 halves (dbuf0) + tile1 B-halves (dbuf1); wait all but 4
  STAGE_A_H0(0); STAGE_A_H1(0); STAGE_B_H0(0); STAGE_B_H1(0);
  STAGE_B_H0(32768); STAGE_B_H1(32768);
  WAIT_VM4();
  BARRIER();

  // ---- fragment read indices (16-B units, typed LDS -> guaranteed ds_read_b128) ----
  const int rc0 = m * 8 + ((quad)     ^ (m & 7));
  const int rc1 = m * 8 + ((quad + 4) ^ (m & 7));
  const int aI0 = wmi * 1024 + rc0;
  const int aI1 = wmi * 1024 + rc1;
  const int bI0 = 4096 + (wni >> 1) * 1024 + (wni & 1) * 512 + rc0;
  const int bI1 = 4096 + (wni >> 1) * 1024 + (wni & 1) * 512 + rc1;

  floatx4 acc[8][4] = {};

  for (int t = 0; t < nt; ++t) {
    const int dI = (t & 1) << 11;   // dbuf offset in 16-B units (32768 B)
    const int dB = dI << 4;         // dbuf offset in bytes
    const int dN = dB ^ 32768;      // other dbuf (bytes)
    const bool notlast = (t < nt - 1);
    const bool notlast2 = (t < nt - 2);
    short8 af[4], bfr[4];

    // ---------------- phase A: kk0, i 0..3 ----------------
#pragma unroll
    for (int i = 0; i < 4; ++i) af[i] = smv[dI + aI0 + i * 128];
#pragma unroll
    for (int j = 0; j < 4; ++j) bfr[j] = smv[dI + bI0 + j * 128];
    if (notlast) STAGE_A_H0(dN);
    BARRIER();
    WAIT_LGKM0();
    SCHED_FENCE();
    __builtin_amdgcn_s_setprio(1);
#pragma unroll
    for (int i = 0; i < 4; ++i)
#pragma unroll
      for (int j = 0; j < 4; ++j) acc[i][j] = MFMA16x16x32(af[i], bfr[j], acc[i][j]);
    __builtin_amdgcn_s_setprio(0);
    BARRIER();

    // ---------------- phase B: kk0, i 4..7 ----------------
#pragma unroll
    for (int i = 0; i < 4; ++i) af[i] = smv[dI + aI0 + 512 + i * 128];
    if (notlast) STAGE_A_H1(dN);
    BARRIER();
    WAIT_LGKM0();
    SCHED_FENCE();
    __builtin_amdgcn_s_setprio(1);
#pragma unroll
    for (int i = 0; i < 4; ++i)
#pragma unroll
      for (int j = 0; j < 4; ++j) acc[i + 4][j] = MFMA16x16x32(af[i], bfr[j], acc[i + 4][j]);
    __builtin_amdgcn_s_setprio(0);
    BARRIER();

    // ---------------- phase C: kk1, i 0..3 ----------------
#pragma unroll
    for (int i = 0; i < 4; ++i) af[i] = smv[dI + aI1 + i * 128];
#pragma unroll
    for (int j = 0; j < 4; ++j) bfr[j] = smv[dI + bI1 + j * 128];
    BARRIER();
    WAIT_LGKM0();
    SCHED_FENCE();
    __builtin_amdgcn_s_setprio(1);
#pragma unroll
    for (int i = 0; i < 4; ++i)
#pragma unroll
      for (int j = 0; j < 4; ++j) acc[i][j] = MFMA16x16x32(af[i], bfr[j], acc[i][j]);
    __builtin_amdgcn_s_setprio(0);
    BARRIER();

    // ---------------- phase D: kk1, i 4..7 ----------------
#pragma unroll
    for (int i = 0; i < 4; ++i) af[i] = smv[dI + aI1 + 512 + i * 128];
    if (notlast2) { STAGE_B_H0(dB); STAGE_B_H1(dB); }
    BARRIER();
    WAIT_LGKM0();
    SCHED_FENCE();
    __builtin_amdgcn_s_setprio(1);
#pragma unroll
    for (int i = 0; i < 4; ++i)
#pragma unroll
      for (int j = 0; j < 4; ++j) acc[i + 4][j] = MFMA16x16x32(af[i], bfr[j], acc[i + 4][j]);
    __builtin_amdgcn_s_setprio(0);
    // tile-boundary wait: counted (keeps t+2's 4 B-loads in flight); drain at tail
    if (notlast2) { WAIT_VM4(); } else { WAIT_VM0(); }
    BARRIER();
  }

#undef STAGE_A_H0
#undef STAGE_A_H1
#undef STAGE_B_H0
#undef STAGE_B_H1

  // ---------------- epilogue: acc -> swizzled LDS (bf16) -> coalesced 16-B stores ----
  // swizzle chi(row,colbyte) = (((row>>2)&3)<<5) ^ (((colbyte>>8)&1)<<4):
  //  write: per-instr XOR = quad<<5 (const per lane-quarter) -> 2-way free
  //  read : quarter-wave spreads (b&3,h) over all 8 chunks -> 2-way free
  {
    ushort* se = (ushort*)smv;
#pragma unroll
    for (int j = 0; j < 4; ++j) {
      const int colE = wni * 64 + j * 16 + m;    // element col within tile
      const int colByte = colE * 2;
      const float bj = bias[col0 + colE];
      const int cswz = (quad << 5) ^ (((colByte >> 8) & 1) << 4);
      const int cb = colByte ^ cswz;
#pragma unroll
      for (int i = 0; i < 8; ++i) {
        const int rw = wmi * 128 + i * 16 + quad * 4;
#pragma unroll
        for (int r = 0; r < 4; ++r) {
          float v = acc[i][j][r] + bj;
          if (act == 1) {
            // tanh-form GELU (overflow-safe)
            float tt = 0.7978845608f * (v + 0.044715f * v * v * v);
            float e2 = __expf(-2.0f * fabsf(tt));
            float th = (1.0f - e2) / (1.0f + e2);
            th = tt < 0.0f ? -th : th;
            v = 0.5f * v * (1.0f + th);
          }
          __hip_bfloat16 bv = __float2bfloat16(v);
          se[((rw + r) * 512 + cb) >> 1] = *(ushort*)&bv;
        }
      }
    }
    __syncthreads();
    const int k2 = lane >> 4;          // 0..3
    const int h = (lane >> 3) & 1;     // half of the 512-B row
    const int b = lane & 7;
    const int row = wave * 32 + b * 4 + k2;
    const size_t gb = (size_t)(row0 + row) * N + col0 + h * 128;
    const int rsw = (((row >> 2) & 3) << 5) ^ (h << 4);
#pragma unroll
    for (int c = 0; c < 16; ++c) {
      const int cb2 = (h * 256 + c * 16) ^ rsw;
      *(short8*)(C + gb + c * 8) = *(const short8*)(smc + row * 512 + cb2);
    }
  }
}

// ---------------------------------------------------------------- fused attention per (b,h)
// qkv fused: row stride 1536; q at col h*64, k at 512+h*64, v at 1024+h*64.
__global__ __launch_bounds__(384) void attn_fused(
    const __hip_bfloat16* __restrict__ qkv,
    const float* __restrict__ mat,
    float* __restrict__ scores,
    __hip_bfloat16* __restrict__ ctx) {
  __shared__ __align__(16) __hip_bfloat16 Ks[96 * 72];   // [l_k][d], pad 64->72
  __shared__ __align__(16) __hip_bfloat16 Vt[64 * 104];  // [d][l_k], pad 96->104
  __shared__ __align__(16) __hip_bfloat16 Ps[96 * 104];  // [l_q][l_k], pad 96->104
  const int bh = blockIdx.x;
  const int b = bh >> 3, h = bh & 7;
  const __hip_bfloat16* qb = qkv + (size_t)b * 96 * 1536 + h * 64;
  const __hip_bfloat16* kb = qb + 512;
  const __hip_bfloat16* vb = qb + 1024;
  const int tid = threadIdx.x;

  // stage K [96][64] -> Ks, 16B chunks
  for (int c = tid; c < 768; c += 384) {
    int row = c >> 3, c8 = (c & 7) * 8;
    *(short8*)&Ks[row * 72 + c8] = *(const short8*)(kb + (size_t)row * 1536 + c8);
  }
  // stage V transposed
  {
    int d = tid & 63;
    for (int l = tid >> 6; l < 96; l += 6) Vt[d * 104 + l] = vb[(size_t)l * 1536 + d];
  }
  __syncthreads();

  const int wave = tid >> 6, lane = tid & 63;
  const int quad = lane >> 4, m = lane & 15;

  // phase 1: S = Q K^T (16 rows per wave, N=96, K=64)
  short8 a0 = *(const short8*)(qb + (size_t)(wave * 16 + m) * 1536 + quad * 8);
  short8 a1 = *(const short8*)(qb + (size_t)(wave * 16 + m) * 1536 + 32 + quad * 8);
  floatx4 s[6];
  const size_t mbase = ((size_t)bh * 96 + wave * 16 + quad * 4) * 96 + m;
#pragma unroll
  for (int ct = 0; ct < 6; ++ct) {
    short8 b0 = *(const short8*)&Ks[(ct * 16 + m) * 72 + quad * 8];
    short8 b1 = *(const short8*)&Ks[(ct * 16 + m) * 72 + 32 + quad * 8];
    floatx4 accv = {};
    accv = MFMA16x16x32(a0, b0, accv);
    accv = MFMA16x16x32(a1, b1, accv);
#pragma unroll
    for (int r = 0; r < 4; ++r) {
      float sv = accv[r] * 0.125f * mat[mbase + (size_t)r * 96 + ct * 16];
      accv[r] = sv;
      scores[mbase + (size_t)r * 96 + ct * 16] = sv;
    }
    s[ct] = accv;
  }

  // softmax over each row
#pragma unroll
  for (int r = 0; r < 4; ++r) {
    float mx = s[0][r];
#pragma unroll
    for (int ct = 1; ct < 6; ++ct) mx = fmaxf(mx, s[ct][r]);
#pragma unroll
    for (int dd = 1; dd < 16; dd <<= 1) mx = fmaxf(mx, __shfl_xor(mx, dd, 64));
    float sum = 0.f;
#pragma unroll
    for (int ct = 0; ct < 6; ++ct) {
      float e = __expf(s[ct][r] - mx);
      s[ct][r] = e;
      sum += e;
    }
#pragma unroll
    for (int dd = 1; dd < 16; dd <<= 1) sum += __shfl_xor(sum, dd, 64);
    float inv = 1.0f / sum;
#pragma unroll
    for (int ct = 0; ct < 6; ++ct)
      Ps[(wave * 16 + quad * 4 + r) * 104 + ct * 16 + m] = __float2bfloat16(s[ct][r] * inv);
  }
  __syncthreads();

  // phase 2: O = P V  (K = 96, 3 k-steps of 32)
  floatx4 o[4] = {};
#pragma unroll
  for (int ks = 0; ks < 3; ++ks) {
    short8 pa = *(const short8*)&Ps[(wave * 16 + m) * 104 + ks * 32 + quad * 8];
#pragma unroll
    for (int ct = 0; ct < 4; ++ct) {
      short8 vv = *(const short8*)&Vt[(ct * 16 + m) * 104 + ks * 32 + quad * 8];
      o[ct] = MFMA16x16x32(pa, vv, o[ct]);
    }
  }
  __hip_bfloat16* cb = ctx + (size_t)b * 96 * 512 + h * 64;
#pragma unroll
  for (int ct = 0; ct < 4; ++ct)
#pragma unroll
    for (int r = 0; r < 4; ++r)
      cb[(size_t)(wave * 16 + quad * 4 + r) * 512 + ct * 16 + m] = __float2bfloat16(o[ct][r]);
}

// ---------------------------------------------------------------- residual + LayerNorm, one block per row (D=512)
template <typename RT, typename OT>
__global__ __launch_bounds__(256) void ln_res(
    const __hip_bfloat16* __restrict__ a, const RT* __restrict__ rsd,
    const float* __restrict__ g, const float* __restrict__ be,
    OT* __restrict__ out) {
  const int row = blockIdx.x;
  const int tid = threadIdx.x;
  const size_t base = (size_t)row * 512 + tid * 2;
  float x0 = __bfloat162float(a[base]) + to_f(rsd[base]);
  float x1 = __bfloat162float(a[base + 1]) + to_f(rsd[base + 1]);
  float s = x0 + x1, s2 = x0 * x0 + x1 * x1;
#pragma unroll
  for (int d = 1; d < 64; d <<= 1) {
    s += __shfl_xor(s, d, 64);
    s2 += __shfl_xor(s2, d, 64);
  }
  __shared__ float red[8];
  const int wave = tid >> 6, lane = tid & 63;
  if (lane == 0) {
    red[wave] = s;
    red[4 + wave] = s2;
  }
  __syncthreads();
  s = red[0] + red[1] + red[2] + red[3];
  s2 = red[4] + red[5] + red[6] + red[7];
  const float mean = s * (1.0f / 512.0f);
  const float var = s2 * (1.0f / 512.0f) - mean * mean;
  const float rstd = rsqrtf(var + 1e-5f);
  st_val(out + base, (x0 - mean) * rstd * g[tid * 2] + be[tid * 2]);
  st_val(out + base + 1, (x1 - mean) * rstd * g[tid * 2 + 1] + be[tid * 2 + 1]);
}

// ---------------------------------------------------------------- launch
extern "C" void kernel_launch(void* const* d_in, const int* in_sizes, int n_in,
                              void* d_out, int out_size, void* d_ws, size_t ws_size,
                              hipStream_t stream) {
  (void)in_sizes; (void)n_in; (void)out_size; (void)ws_size;
  typedef const float* cf;
  typedef __hip_bfloat16* bf;
  cf src = (cf)d_in[0];
  cf Wq = (cf)d_in[1];  cf bq = (cf)d_in[2];
  cf Wk = (cf)d_in[3];  cf bk = (cf)d_in[4];
  cf Wv = (cf)d_in[5];  cf bv = (cf)d_in[6];
  cf mat = (cf)d_in[7];
  cf Wo = (cf)d_in[8];  cf bo = (cf)d_in[9];
  cf g1 = (cf)d_in[10]; cf be1 = (cf)d_in[11];
  cf W1 = (cf)d_in[12]; cf b1 = (cf)d_in[13];
  cf W2 = (cf)d_in[14]; cf b2 = (cf)d_in[15];
  cf g2 = (cf)d_in[16]; cf be2 = (cf)d_in[17];

  char* ws = (char*)d_ws;
  const size_t SZ = (size_t)24576 * 512 * 2;  // 25,165,824 B
  bf qkv = (bf)(ws);                  // [24576][1536] bf16 = 3*SZ
  bf ctx = (bf)(ws + 3 * SZ);
  bf hb  = (bf)(ws);                  // FFN hidden [24576][2048] = 4*SZ; qkv+ctx dead by then
  bf srcb = (bf)(ws + 4 * SZ);        // dead after qkv-gemm
  bf tmp = (bf)(ws + 4 * SZ);         // wo out -> ln1; later ffn2 out -> ln2
  bf xb  = (bf)(ws + 5 * SZ);         // post-LN1 x
  char* wt = ws + 6 * SZ;
  bf WqkvT = (bf)(wt);                          // [1536][512] bf16
  bf WoT = (bf)(wt + 1572864);
  bf W1T = (bf)(wt + 1572864 + 524288);         // [2048][512]
  bf W2T = (bf)(wt + 1572864 + 524288 + 2097152);  // [512][2048]
  float* bqkv = (float*)(wt + 1572864 + 524288 + 2097152 + 2097152);

  float* yout = (float*)d_out;
  float* scout = (float*)d_out + 12582912;  // scores after y

  cvt_f32_bf16<<<12288, 256, 0, stream>>>((const float4*)src, (ushort*)srcb);
  concat3<<<6, 256, 0, stream>>>(bq, bk, bv, bqkv);

  dim3 tb(32, 8);
  transpose_cvt<<<dim3(16, 16), tb, 0, stream>>>(Wq, WqkvT, 512, 512);
  transpose_cvt<<<dim3(16, 16), tb, 0, stream>>>(Wk, WqkvT + 512 * 512, 512, 512);
  transpose_cvt<<<dim3(16, 16), tb, 0, stream>>>(Wv, WqkvT + 1024 * 512, 512, 512);
  transpose_cvt<<<dim3(16, 16), tb, 0, stream>>>(Wo, WoT, 512, 512);
  transpose_cvt<<<dim3(64, 16), tb, 0, stream>>>(W1, W1T, 512, 2048);
  transpose_cvt<<<dim3(16, 64), tb, 0, stream>>>(W2, W2T, 2048, 512);

  // 256x256-tile 8-phase GEMMs; tiles_x = N/256, grid = (M/256)*(N/256), all %8==0
  gemm256<<<576, 512, 0, stream>>>(srcb, WqkvT, bqkv, qkv, 24576, 1536, 512, 0, 6);

  attn_fused<<<2048, 384, 0, stream>>>(qkv, mat, scout, ctx);

  gemm256<<<192, 512, 0, stream>>>(ctx, WoT, bo, tmp, 24576, 512, 512, 0, 2);
  ln_res<float, __hip_bfloat16><<<24576, 256, 0, stream>>>(tmp, src, g1, be1, xb);
  gemm256<<<768, 512, 0, stream>>>(xb, W1T, b1, hb, 24576, 2048, 512, 1, 8);
  gemm256<<<192, 512, 0, stream>>>(hb, W2T, b2, tmp, 24576, 512, 2048, 0, 2);
  ln_res<__hip_bfloat16, float><<<24576, 256, 0, stream>>>(tmp, xb, g2, be2, yout);
}

// Round 4
// 612.548 us; speedup vs baseline: 1.0182x; 1.0182x over previous
//
#include <hip/hip_runtime.h>
#include <hip/hip_bf16.h>
#include <math.h>

typedef __attribute__((ext_vector_type(8))) short short8;
typedef __attribute__((ext_vector_type(4))) float floatx4;

// ---------------------------------------------------------------- helpers
__device__ __forceinline__ void load_lds16(const void* g, void* l) {
  __builtin_amdgcn_global_load_lds(
      (__attribute__((address_space(1))) void*)(g),
      (__attribute__((address_space(3))) void*)(l), 16, 0, 0);
}

#define MFMA16x16x32(a, b, c) __builtin_amdgcn_mfma_f32_16x16x32_bf16((a), (b), (c), 0, 0, 0)
#define BARRIER() __builtin_amdgcn_s_barrier()
#define WAIT_LGKM0() asm volatile("s_waitcnt lgkmcnt(0)" ::: "memory")
#define WAIT_VM8() asm volatile("s_waitcnt vmcnt(8)" ::: "memory")
#define WAIT_VM0() asm volatile("s_waitcnt vmcnt(0)" ::: "memory")
#define SCHED_FENCE() __builtin_amdgcn_sched_barrier(0)

__device__ __forceinline__ float to_f(float x) { return x; }
__device__ __forceinline__ float to_f(__hip_bfloat16 x) { return __bfloat162float(x); }
__device__ __forceinline__ void st_val(float* p, float v) { *p = v; }
__device__ __forceinline__ void st_val(__hip_bfloat16* p, float v) { *p = __float2bfloat16(v); }

// ---------------------------------------------------------------- fp32 -> bf16 elementwise (src)
__global__ __launch_bounds__(256) void cvt_f32_bf16(const float4* __restrict__ in,
                                                    ushort* __restrict__ out) {
  int i = blockIdx.x * 256 + threadIdx.x;
  float4 v = in[i];
  ushort4 o;
  __hip_bfloat16 b0 = __float2bfloat16(v.x);
  __hip_bfloat16 b1 = __float2bfloat16(v.y);
  __hip_bfloat16 b2 = __float2bfloat16(v.z);
  __hip_bfloat16 b3 = __float2bfloat16(v.w);
  o.x = *(ushort*)&b0; o.y = *(ushort*)&b1; o.z = *(ushort*)&b2; o.w = *(ushort*)&b3;
  *(ushort4*)(out + 4 * i) = o;
}

// ---------------------------------------------------------------- concat 3 bias vectors (512 each)
__global__ void concat3(const float* __restrict__ a, const float* __restrict__ b,
                        const float* __restrict__ c, float* __restrict__ o) {
  int i = blockIdx.x * 256 + threadIdx.x;  // 0..1535
  o[i] = i < 512 ? a[i] : (i < 1024 ? b[i - 512] : c[i - 1024]);
}

// ---------------------------------------------------------------- fp32 weights -> bf16 transposed
__global__ void transpose_cvt(const float* __restrict__ in,
                              __hip_bfloat16* __restrict__ out, int R, int C) {
  __shared__ __hip_bfloat16 tile[32][33];
  int bx = blockIdx.x * 32, by = blockIdx.y * 32;
  int tx = threadIdx.x, ty = threadIdx.y;  // (32,8)
  for (int i = ty; i < 32; i += 8)
    tile[i][tx] = __float2bfloat16(in[(size_t)(by + i) * C + bx + tx]);
  __syncthreads();
  for (int i = ty; i < 32; i += 8) out[(size_t)(bx + i) * R + by + tx] = tile[tx][i];
}

// ---------------------------------------------------------------- GEMM: C[M,N] = A[M,K] @ BT[N,K]^T + bias, opt GELU
// 256x256 tile, BK=64, 8 waves (2M x 4N), per-wave 128x64 output (acc[8][4]).
// 2 phases per K-tile (kk0, kk1), 32 MFMA per phase, 4 barriers/tile.
// Whole-tile prefetch: all 8 loads for tile t+2 issued after P1's closing
// barrier (hard-safe: every wave's dbuf(t) reads lgkm-drained before its MFMA,
// which precedes that barrier). vmcnt(8) at tile end keeps t+2 in flight,
// t+1 landed; drain vmcnt(0) only for the last two tiles.
// LDS swizzle (counter-verified r3): 16-B chunk c holds global chunk c^(row&7);
// stage = linear global_load_lds dest + pre-swizzled GLOBAL source chunk
// (l&7)^((l>>3)&7); read chunk' = (quad+4*kk)^(m&7) -> 2-way = conflict-free.
// LDS: A[2 dbuf][2 half][128 rows][64 kk] = 64 KB @0; B same @65536. 128 KB.
__global__ __launch_bounds__(512) void gemm256(
    const __hip_bfloat16* __restrict__ A,
    const __hip_bfloat16* __restrict__ BT,
    const float* __restrict__ bias,
    __hip_bfloat16* __restrict__ C,
    int M, int N, int K, int act, int tiles_x) {
  (void)M;
  __shared__ __align__(16) short8 smv[8192];  // 128 KB
  char* smc = (char*)smv;
  const int tid = threadIdx.x;
  const int wave = tid >> 6, lane = tid & 63;
  const int quad = lane >> 4, m = lane & 15;
  const int wmi = wave >> 2, wni = wave & 3;
  // bijective XCD-chunked swizzle (grid % 8 == 0 for all call sites)
  const int nwg = gridDim.x;
  const int wg = (blockIdx.x & 7) * (nwg >> 3) + (blockIdx.x >> 3);
  const int row0 = (wg / tiles_x) * 256;
  const int col0 = (wg % tiles_x) * 256;
  const int nt = K >> 6;

  // ---- staging source addressing (pre-swizzled chunk) ----
  const int colb = (((lane & 7) ^ ((lane >> 3) & 7)) << 4);
  const int rbase = wave * 16 + (lane >> 3);  // rows of chunk r=0; r=1 adds 8
  const char* pA0 = (const char*)(A + (size_t)(row0 + rbase) * K) + colb;
  const char* pA1 = (const char*)(A + (size_t)(row0 + rbase + 8) * K) + colb;
  const char* pA2 = (const char*)(A + (size_t)(row0 + 128 + rbase) * K) + colb;
  const char* pA3 = (const char*)(A + (size_t)(row0 + 128 + rbase + 8) * K) + colb;
  const char* pB0 = (const char*)(BT + (size_t)(col0 + rbase) * K) + colb;
  const char* pB1 = (const char*)(BT + (size_t)(col0 + rbase + 8) * K) + colb;
  const char* pB2 = (const char*)(BT + (size_t)(col0 + 128 + rbase) * K) + colb;
  const char* pB3 = (const char*)(BT + (size_t)(col0 + 128 + rbase + 8) * K) + colb;
  const int c0 = wave * 2048;        // LDS chunk r=0 (wave-uniform)
  const int c1 = wave * 2048 + 1024; // LDS chunk r=1

  // all 8 loads of one K-tile (A both halves + B both halves) into dbuf at byte d
#define STAGE_TILE(d)                                  \
  do {                                                 \
    load_lds16(pA0, smc + (d) + c0);                   \
    load_lds16(pA1, smc + (d) + c1);                   \
    load_lds16(pA2, smc + (d) + 16384 + c0);           \
    load_lds16(pA3, smc + (d) + 16384 + c1);           \
    load_lds16(pB0, smc + 65536 + (d) + c0);           \
    load_lds16(pB1, smc + 65536 + (d) + c1);           \
    load_lds16(pB2, smc + 65536 + (d) + 16384 + c0);   \
    load_lds16(pB3, smc + 65536 + (d) + 16384 + c1);   \
    pA0 += 128; pA1 += 128; pA2 += 128; pA3 += 128;    \
    pB0 += 128; pB1 += 128; pB2 += 128; pB3 += 128;    \
  } while (0)

  // prologue: tile0 -> dbuf0, tile1 -> dbuf1; wait tile0 landed (8 in flight)
  STAGE_TILE(0);
  STAGE_TILE(32768);
  WAIT_VM8();
  BARRIER();

  // ---- fragment read indices (16-B units, typed LDS -> ds_read_b128) ----
  const int rc0 = m * 8 + ((quad)     ^ (m & 7));
  const int rc1 = m * 8 + ((quad + 4) ^ (m & 7));
  const int aI0 = wmi * 1024 + rc0;
  const int aI1 = wmi * 1024 + rc1;
  const int bI0 = 4096 + (wni >> 1) * 1024 + (wni & 1) * 512 + rc0;
  const int bI1 = 4096 + (wni >> 1) * 1024 + (wni & 1) * 512 + rc1;

  floatx4 acc[8][4] = {};

  for (int t = 0; t < nt; ++t) {
    const int dI = (t & 1) << 11;   // dbuf offset in 16-B units (32768 B)
    const int dB = dI << 4;         // dbuf offset in bytes (t and t+2 share)
    short8 af[8], bfr[4];

    // ---------------- phase P0: kk0, i 0..7 ----------------
#pragma unroll
    for (int i = 0; i < 8; ++i) af[i] = smv[dI + aI0 + i * 128];
#pragma unroll
    for (int j = 0; j < 4; ++j) bfr[j] = smv[dI + bI0 + j * 128];
    BARRIER();
    WAIT_LGKM0();
    SCHED_FENCE();
    __builtin_amdgcn_s_setprio(1);
#pragma unroll
    for (int i = 0; i < 8; ++i)
#pragma unroll
      for (int j = 0; j < 4; ++j) acc[i][j] = MFMA16x16x32(af[i], bfr[j], acc[i][j]);
    __builtin_amdgcn_s_setprio(0);

    // ---------------- phase P1: kk1, i 0..7 ----------------
#pragma unroll
    for (int i = 0; i < 8; ++i) af[i] = smv[dI + aI1 + i * 128];
#pragma unroll
    for (int j = 0; j < 4; ++j) bfr[j] = smv[dI + bI1 + j * 128];
    BARRIER();
    WAIT_LGKM0();
    SCHED_FENCE();
    __builtin_amdgcn_s_setprio(1);
#pragma unroll
    for (int i = 0; i < 8; ++i)
#pragma unroll
      for (int j = 0; j < 4; ++j) acc[i][j] = MFMA16x16x32(af[i], bfr[j], acc[i][j]);
    __builtin_amdgcn_s_setprio(0);
    BARRIER();  // all waves' dbuf(t) reads drained before their MFMA -> safe to overwrite

    // ---------------- tile-end: prefetch t+2 into this dbuf ----------------
    if (t < nt - 2) {
      STAGE_TILE(dB);
      WAIT_VM8();   // t+1 landed (its 8 loads are the oldest); t+2 in flight
    } else {
      WAIT_VM0();   // tail: drain remaining loads
    }
    BARRIER();
  }

#undef STAGE_TILE

  // ---------------- epilogue: direct global stores ----------------
#pragma unroll
  for (int j = 0; j < 4; ++j) {
    const int col = col0 + wni * 64 + j * 16 + m;
    const float bj = bias[col];
#pragma unroll
    for (int i = 0; i < 8; ++i) {
      const int rowb = row0 + wmi * 128 + i * 16 + quad * 4;
#pragma unroll
      for (int r = 0; r < 4; ++r) {
        float v = acc[i][j][r] + bj;
        if (act == 1) {
          // tanh-form GELU (overflow-safe)
          float tt = 0.7978845608f * (v + 0.044715f * v * v * v);
          float e2 = __expf(-2.0f * fabsf(tt));
          float th = (1.0f - e2) / (1.0f + e2);
          th = tt < 0.0f ? -th : th;
          v = 0.5f * v * (1.0f + th);
        }
        C[(size_t)(rowb + r) * N + col] = __float2bfloat16(v);
      }
    }
  }
}

// ---------------------------------------------------------------- fused attention per (b,h)
// qkv fused: row stride 1536; q at col h*64, k at 512+h*64, v at 1024+h*64.
__global__ __launch_bounds__(384) void attn_fused(
    const __hip_bfloat16* __restrict__ qkv,
    const float* __restrict__ mat,
    float* __restrict__ scores,
    __hip_bfloat16* __restrict__ ctx) {
  __shared__ __align__(16) __hip_bfloat16 Ks[96 * 72];   // [l_k][d], pad 64->72
  __shared__ __align__(16) __hip_bfloat16 Vt[64 * 104];  // [d][l_k], pad 96->104
  __shared__ __align__(16) __hip_bfloat16 Ps[96 * 104];  // [l_q][l_k], pad 96->104
  const int bh = blockIdx.x;
  const int b = bh >> 3, h = bh & 7;
  const __hip_bfloat16* qb = qkv + (size_t)b * 96 * 1536 + h * 64;
  const __hip_bfloat16* kb = qb + 512;
  const __hip_bfloat16* vb = qb + 1024;
  const int tid = threadIdx.x;

  // stage K [96][64] -> Ks, 16B chunks
  for (int c = tid; c < 768; c += 384) {
    int row = c >> 3, c8 = (c & 7) * 8;
    *(short8*)&Ks[row * 72 + c8] = *(const short8*)(kb + (size_t)row * 1536 + c8);
  }
  // stage V transposed
  {
    int d = tid & 63;
    for (int l = tid >> 6; l < 96; l += 6) Vt[d * 104 + l] = vb[(size_t)l * 1536 + d];
  }
  __syncthreads();

  const int wave = tid >> 6, lane = tid & 63;
  const int quad = lane >> 4, m = lane & 15;

  // phase 1: S = Q K^T (16 rows per wave, N=96, K=64)
  short8 a0 = *(const short8*)(qb + (size_t)(wave * 16 + m) * 1536 + quad * 8);
  short8 a1 = *(const short8*)(qb + (size_t)(wave * 16 + m) * 1536 + 32 + quad * 8);
  floatx4 s[6];
  const size_t mbase = ((size_t)bh * 96 + wave * 16 + quad * 4) * 96 + m;
#pragma unroll
  for (int ct = 0; ct < 6; ++ct) {
    short8 b0 = *(const short8*)&Ks[(ct * 16 + m) * 72 + quad * 8];
    short8 b1 = *(const short8*)&Ks[(ct * 16 + m) * 72 + 32 + quad * 8];
    floatx4 accv = {};
    accv = MFMA16x16x32(a0, b0, accv);
    accv = MFMA16x16x32(a1, b1, accv);
#pragma unroll
    for (int r = 0; r < 4; ++r) {
      float sv = accv[r] * 0.125f * mat[mbase + (size_t)r * 96 + ct * 16];
      accv[r] = sv;
      scores[mbase + (size_t)r * 96 + ct * 16] = sv;
    }
    s[ct] = accv;
  }

  // softmax over each row
#pragma unroll
  for (int r = 0; r < 4; ++r) {
    float mx = s[0][r];
#pragma unroll
    for (int ct = 1; ct < 6; ++ct) mx = fmaxf(mx, s[ct][r]);
#pragma unroll
    for (int dd = 1; dd < 16; dd <<= 1) mx = fmaxf(mx, __shfl_xor(mx, dd, 64));
    float sum = 0.f;
#pragma unroll
    for (int ct = 0; ct < 6; ++ct) {
      float e = __expf(s[ct][r] - mx);
      s[ct][r] = e;
      sum += e;
    }
#pragma unroll
    for (int dd = 1; dd < 16; dd <<= 1) sum += __shfl_xor(sum, dd, 64);
    float inv = 1.0f / sum;
#pragma unroll
    for (int ct = 0; ct < 6; ++ct)
      Ps[(wave * 16 + quad * 4 + r) * 104 + ct * 16 + m] = __float2bfloat16(s[ct][r] * inv);
  }
  __syncthreads();

  // phase 2: O = P V  (K = 96, 3 k-steps of 32)
  floatx4 o[4] = {};
#pragma unroll
  for (int ks = 0; ks < 3; ++ks) {
    short8 pa = *(const short8*)&Ps[(wave * 16 + m) * 104 + ks * 32 + quad * 8];
#pragma unroll
    for (int ct = 0; ct < 4; ++ct) {
      short8 vv = *(const short8*)&Vt[(ct * 16 + m) * 104 + ks * 32 + quad * 8];
      o[ct] = MFMA16x16x32(pa, vv, o[ct]);
    }
  }
  __hip_bfloat16* cb = ctx + (size_t)b * 96 * 512 + h * 64;
#pragma unroll
  for (int ct = 0; ct < 4; ++ct)
#pragma unroll
    for (int r = 0; r < 4; ++r)
      cb[(size_t)(wave * 16 + quad * 4 + r) * 512 + ct * 16 + m] = __float2bfloat16(o[ct][r]);
}

// ---------------------------------------------------------------- residual + LayerNorm, one block per row (D=512)
template <typename RT, typename OT>
__global__ __launch_bounds__(256) void ln_res(
    const __hip_bfloat16* __restrict__ a, const RT* __restrict__ rsd,
    const float* __restrict__ g, const float* __restrict__ be,
    OT* __restrict__ out) {
  const int row = blockIdx.x;
  const int tid = threadIdx.x;
  const size_t base = (size_t)row * 512 + tid * 2;
  float x0 = __bfloat162float(a[base]) + to_f(rsd[base]);
  float x1 = __bfloat162float(a[base + 1]) + to_f(rsd[base + 1]);
  float s = x0 + x1, s2 = x0 * x0 + x1 * x1;
#pragma unroll
  for (int d = 1; d < 64; d <<= 1) {
    s += __shfl_xor(s, d, 64);
    s2 += __shfl_xor(s2, d, 64);
  }
  __shared__ float red[8];
  const int wave = tid >> 6, lane = tid & 63;
  if (lane == 0) {
    red[wave] = s;
    red[4 + wave] = s2;
  }
  __syncthreads();
  s = red[0] + red[1] + red[2] + red[3];
  s2 = red[4] + red[5] + red[6] + red[7];
  const float mean = s * (1.0f / 512.0f);
  const float var = s2 * (1.0f / 512.0f) - mean * mean;
  const float rstd = rsqrtf(var + 1e-5f);
  st_val(out + base, (x0 - mean) * rstd * g[tid * 2] + be[tid * 2]);
  st_val(out + base + 1, (x1 - mean) * rstd * g[tid * 2 + 1] + be[tid * 2 + 1]);
}

// ---------------------------------------------------------------- launch
extern "C" void kernel_launch(void* const* d_in, const int* in_sizes, int n_in,
                              void* d_out, int out_size, void* d_ws, size_t ws_size,
                              hipStream_t stream) {
  (void)in_sizes; (void)n_in; (void)out_size; (void)ws_size;
  typedef const float* cf;
  typedef __hip_bfloat16* bf;
  cf src = (cf)d_in[0];
  cf Wq = (cf)d_in[1];  cf bq = (cf)d_in[2];
  cf Wk = (cf)d_in[3];  cf bk = (cf)d_in[4];
  cf Wv = (cf)d_in[5];  cf bv = (cf)d_in[6];
  cf mat = (cf)d_in[7];
  cf Wo = (cf)d_in[8];  cf bo = (cf)d_in[9];
  cf g1 = (cf)d_in[10]; cf be1 = (cf)d_in[11];
  cf W1 = (cf)d_in[12]; cf b1 = (cf)d_in[13];
  cf W2 = (cf)d_in[14]; cf b2 = (cf)d_in[15];
  cf g2 = (cf)d_in[16]; cf be2 = (cf)d_in[17];

  char* ws = (char*)d_ws;
  const size_t SZ = (size_t)24576 * 512 * 2;  // 25,165,824 B
  bf qkv = (bf)(ws);                  // [24576][1536] bf16 = 3*SZ
  bf ctx = (bf)(ws + 3 * SZ);
  bf hb  = (bf)(ws);                  // FFN hidden [24576][2048] = 4*SZ; qkv+ctx dead by then
  bf srcb = (bf)(ws + 4 * SZ);        // dead after qkv-gemm
  bf tmp = (bf)(ws + 4 * SZ);         // wo out -> ln1; later ffn2 out -> ln2
  bf xb  = (bf)(ws + 5 * SZ);         // post-LN1 x
  char* wt = ws + 6 * SZ;
  bf WqkvT = (bf)(wt);                          // [1536][512] bf16
  bf WoT = (bf)(wt + 1572864);
  bf W1T = (bf)(wt + 1572864 + 524288);         // [2048][512]
  bf W2T = (bf)(wt + 1572864 + 524288 + 2097152);  // [512][2048]
  float* bqkv = (float*)(wt + 1572864 + 524288 + 2097152 + 2097152);

  float* yout = (float*)d_out;
  float* scout = (float*)d_out + 12582912;  // scores after y

  cvt_f32_bf16<<<12288, 256, 0, stream>>>((const float4*)src, (ushort*)srcb);
  concat3<<<6, 256, 0, stream>>>(bq, bk, bv, bqkv);

  dim3 tb(32, 8);
  transpose_cvt<<<dim3(16, 16), tb, 0, stream>>>(Wq, WqkvT, 512, 512);
  transpose_cvt<<<dim3(16, 16), tb, 0, stream>>>(Wk, WqkvT + 512 * 512, 512, 512);
  transpose_cvt<<<dim3(16, 16), tb, 0, stream>>>(Wv, WqkvT + 1024 * 512, 512, 512);
  transpose_cvt<<<dim3(16, 16), tb, 0, stream>>>(Wo, WoT, 512, 512);
  transpose_cvt<<<dim3(64, 16), tb, 0, stream>>>(W1, W1T, 512, 2048);
  transpose_cvt<<<dim3(16, 64), tb, 0, stream>>>(W2, W2T, 2048, 512);

  // 256x256-tile 2-phase GEMMs; tiles_x = N/256, grid = (M/256)*(N/256), all %8==0
  gemm256<<<576, 512, 0, stream>>>(srcb, WqkvT, bqkv, qkv, 24576, 1536, 512, 0, 6);

  attn_fused<<<2048, 384, 0, stream>>>(qkv, mat, scout, ctx);

  gemm256<<<192, 512, 0, stream>>>(ctx, WoT, bo, tmp, 24576, 512, 512, 0, 2);
  ln_res<float, __hip_bfloat16><<<24576, 256, 0, stream>>>(tmp, src, g1, be1, xb);
  gemm256<<<768, 512, 0, stream>>>(xb, W1T, b1, hb, 24576, 2048, 512, 1, 8);
  gemm256<<<192, 512, 0, stream>>>(hb, W2T, b2, tmp, 24576, 512, 2048, 0, 2);
  ln_res<__hip_bfloat16, float><<<24576, 256, 0, stream>>>(tmp, xb, g2, be2, yout);
}

// Round 6
// 595.016 us; speedup vs baseline: 1.0482x; 1.0295x over previous
//
#include <hip/hip_runtime.h>
#include <hip/hip_bf16.h>
#include <math.h>

typedef __attribute__((ext_vector_type(8))) short short8;
typedef __attribute__((ext_vector_type(4))) float floatx4;

// ---------------------------------------------------------------- helpers
__device__ __forceinline__ void load_lds16(const void* g, void* l) {
  __builtin_amdgcn_global_load_lds(
      (__attribute__((address_space(1))) void*)(g),
      (__attribute__((address_space(3))) void*)(l), 16, 0, 0);
}

#define MFMA16x16x32(a, b, c) __builtin_amdgcn_mfma_f32_16x16x32_bf16((a), (b), (c), 0, 0, 0)
#define BARRIER() __builtin_amdgcn_s_barrier()
#define WAIT_LGKM0() asm volatile("s_waitcnt lgkmcnt(0)" ::: "memory")
#define WAIT_LGKM8() asm volatile("s_waitcnt lgkmcnt(8)" ::: "memory")
#define WAIT_VM4() asm volatile("s_waitcnt vmcnt(4)" ::: "memory")
#define WAIT_VM0() asm volatile("s_waitcnt vmcnt(0)" ::: "memory")
#define SCHED_FENCE() __builtin_amdgcn_sched_barrier(0)

__device__ __forceinline__ float to_f(float x) { return x; }
__device__ __forceinline__ float to_f(__hip_bfloat16 x) { return __bfloat162float(x); }
__device__ __forceinline__ void st_val(float* p, float v) { *p = v; }
__device__ __forceinline__ void st_val(__hip_bfloat16* p, float v) { *p = __float2bfloat16(v); }

// ---------------------------------------------------------------- fp32 -> bf16 elementwise (src)
__global__ __launch_bounds__(256) void cvt_f32_bf16(const float4* __restrict__ in,
                                                    ushort* __restrict__ out) {
  int i = blockIdx.x * 256 + threadIdx.x;
  float4 v = in[i];
  ushort4 o;
  __hip_bfloat16 b0 = __float2bfloat16(v.x);
  __hip_bfloat16 b1 = __float2bfloat16(v.y);
  __hip_bfloat16 b2 = __float2bfloat16(v.z);
  __hip_bfloat16 b3 = __float2bfloat16(v.w);
  o.x = *(ushort*)&b0; o.y = *(ushort*)&b1; o.z = *(ushort*)&b2; o.w = *(ushort*)&b3;
  *(ushort4*)(out + 4 * i) = o;
}

// ---------------------------------------------------------------- concat 3 bias vectors (512 each)
__global__ void concat3(const float* __restrict__ a, const float* __restrict__ b,
                        const float* __restrict__ c, float* __restrict__ o) {
  int i = blockIdx.x * 256 + threadIdx.x;  // 0..1535
  o[i] = i < 512 ? a[i] : (i < 1024 ? b[i - 512] : c[i - 1024]);
}

// ---------------------------------------------------------------- fp32 weights -> bf16 transposed
__global__ void transpose_cvt(const float* __restrict__ in,
                              __hip_bfloat16* __restrict__ out, int R, int C) {
  __shared__ __hip_bfloat16 tile[32][33];
  int bx = blockIdx.x * 32, by = blockIdx.y * 32;
  int tx = threadIdx.x, ty = threadIdx.y;  // (32,8)
  for (int i = ty; i < 32; i += 8)
    tile[i][tx] = __float2bfloat16(in[(size_t)(by + i) * C + bx + tx]);
  __syncthreads();
  for (int i = ty; i < 32; i += 8) out[(size_t)(bx + i) * R + by + tx] = tile[tx][i];
}

// ---------------------------------------------------------------- GEMM: C[M,N] = A[M,K] @ BT[N,K]^T + bias, opt GELU
// 256x256 tile, BK=64, 8 waves (2M x 4N), per-wave 128x64 output (acc[8][4]).
// m201-style 8-phase schedule: iteration = 2 K-tiles (even tile in db0, odd in
// db1). Each phase: {4 ds_read (ph1/5 also 8 B-reads + lgkmcnt(8)) || 1
// half-tile global_load_lds stage -> barrier -> lgkmcnt(0) -> setprio(1) ->
// 16 MFMA -> setprio(0) -> barrier}. Stage ring (slot freed 1+ barrier before
// write): P1/2: A(2s+1)->db1, P3/4: B(2s+2)->db0, P5/6: A(2s+2)->db0,
// P7/8: B(2s+3)->db1. Counted vmcnt(4) at phases 4 & 8 only (ledger: 12
// outstanding -> keep 4 not-yet-needed); vmcnt(0) at phase 4 of last iter
// (only 8 outstanding there, vmcnt(4) would leave A in flight -> hazard).
// LDS swizzle (counter-verified r3/r4: conflicts=0): 16-B chunk c holds global
// chunk c^(row&7); stage = linear LDS dest + pre-swizzled GLOBAL source chunk
// (l&7)^((l>>3)&7); read chunk' = (quad+4*kk)^(m&7) -> 2-way = free.
// LDS: A[2 dbuf][2 half][128 rows][64 kk] = 64 KB @0; B same @65536. 128 KB.
__global__ __launch_bounds__(512) void gemm256(
    const __hip_bfloat16* __restrict__ A,
    const __hip_bfloat16* __restrict__ BT,
    const float* __restrict__ bias,
    __hip_bfloat16* __restrict__ C,
    int M, int N, int K, int act, int tiles_x) {
  (void)M;
  __shared__ __align__(16) short8 smv[8192];  // 128 KB
  char* smc = (char*)smv;
  const int tid = threadIdx.x;
  const int wave = tid >> 6, lane = tid & 63;
  const int quad = lane >> 4, m = lane & 15;
  const int wmi = wave >> 2, wni = wave & 3;
  // bijective XCD-chunked swizzle (grid % 8 == 0 for all call sites)
  const int nwg = gridDim.x;
  const int wg = (blockIdx.x & 7) * (nwg >> 3) + (blockIdx.x >> 3);
  const int row0 = (wg / tiles_x) * 256;
  const int col0 = (wg % tiles_x) * 256;
  const int ns = K >> 7;  // iterations of 2 K-tiles

  // ---- staging source addressing (pre-swizzled chunk) ----
  const int colb = (((lane & 7) ^ ((lane >> 3) & 7)) << 4);
  const int rbase = wave * 16 + (lane >> 3);  // rows of chunk r=0; r=1 adds 8
  const char* pA0 = (const char*)(A + (size_t)(row0 + rbase) * K) + colb;
  const char* pA1 = (const char*)(A + (size_t)(row0 + rbase + 8) * K) + colb;
  const char* pA2 = (const char*)(A + (size_t)(row0 + 128 + rbase) * K) + colb;
  const char* pA3 = (const char*)(A + (size_t)(row0 + 128 + rbase + 8) * K) + colb;
  const char* pB0 = (const char*)(BT + (size_t)(col0 + rbase) * K) + colb;
  const char* pB1 = (const char*)(BT + (size_t)(col0 + rbase + 8) * K) + colb;
  const char* pB2 = (const char*)(BT + (size_t)(col0 + 128 + rbase) * K) + colb;
  const char* pB3 = (const char*)(BT + (size_t)(col0 + 128 + rbase + 8) * K) + colb;
  const int c0 = wave * 2048;        // LDS chunk r=0 (wave-uniform)
  const int c1 = wave * 2048 + 1024; // LDS chunk r=1

  // half-tile stages: 2 load_lds16 per thread, pointer advances 1 K-tile
#define STAGE_A_H0(d)                          \
  do {                                         \
    load_lds16(pA0, smc + (d) + c0);           \
    load_lds16(pA1, smc + (d) + c1);           \
    pA0 += 128; pA1 += 128;                    \
  } while (0)
#define STAGE_A_H1(d)                          \
  do {                                         \
    load_lds16(pA2, smc + (d) + 16384 + c0);   \
    load_lds16(pA3, smc + (d) + 16384 + c1);   \
    pA2 += 128; pA3 += 128;                    \
  } while (0)
#define STAGE_B_H0(d)                              \
  do {                                             \
    load_lds16(pB0, smc + 65536 + (d) + c0);       \
    load_lds16(pB1, smc + 65536 + (d) + c1);       \
    pB0 += 128; pB1 += 128;                        \
  } while (0)
#define STAGE_B_H1(d)                                  \
  do {                                                 \
    load_lds16(pB2, smc + 65536 + (d) + 16384 + c0);   \
    load_lds16(pB3, smc + 65536 + (d) + 16384 + c1);   \
    pB3 += 128; pB2 += 128;                            \
  } while (0)

  // prologue: t0 A+B -> db0, t1 B -> db1; wait t0 landed (t1-B = 4 in flight)
  STAGE_A_H0(0); STAGE_A_H1(0); STAGE_B_H0(0); STAGE_B_H1(0);
  STAGE_B_H0(32768); STAGE_B_H1(32768);
  WAIT_VM4();
  BARRIER();

  // ---- fragment read indices (16-B units, typed LDS -> ds_read_b128) ----
  const int rc0 = m * 8 + ((quad)     ^ (m & 7));
  const int rc1 = m * 8 + ((quad + 4) ^ (m & 7));
  const int aI0 = wmi * 1024 + rc0;
  const int aI1 = wmi * 1024 + rc1;
  const int bI0 = 4096 + (wni >> 1) * 1024 + (wni & 1) * 512 + rc0;
  const int bI1 = 4096 + (wni >> 1) * 1024 + (wni & 1) * 512 + rc1;

  floatx4 acc[8][4] = {};
  short8 aF[4], bF0[4], bF1[4];

  // phase with B loads (rows 0,1 of the wave's half)
#define PHASE_B(dRd, STAGE_STMT)                                      \
  do {                                                                \
    aF[0] = smv[(dRd) + aI0];                                         \
    aF[1] = smv[(dRd) + aI1];                                         \
    aF[2] = smv[(dRd) + aI0 + 128];                                   \
    aF[3] = smv[(dRd) + aI1 + 128];                                   \
    _Pragma("unroll")                                                 \
    for (int j = 0; j < 4; ++j) {                                     \
      bF0[j] = smv[(dRd) + bI0 + j * 128];                            \
      bF1[j] = smv[(dRd) + bI1 + j * 128];                            \
    }                                                                 \
    STAGE_STMT;                                                       \
    WAIT_LGKM8();                                                     \
    BARRIER();                                                        \
    WAIT_LGKM0();                                                     \
    SCHED_FENCE();                                                    \
    __builtin_amdgcn_s_setprio(1);                                    \
    _Pragma("unroll")                                                 \
    for (int j = 0; j < 4; ++j) {                                     \
      acc[0][j] = MFMA16x16x32(aF[0], bF0[j], acc[0][j]);             \
      acc[0][j] = MFMA16x16x32(aF[1], bF1[j], acc[0][j]);             \
      acc[1][j] = MFMA16x16x32(aF[2], bF0[j], acc[1][j]);             \
      acc[1][j] = MFMA16x16x32(aF[3], bF1[j], acc[1][j]);             \
    }                                                                 \
    __builtin_amdgcn_s_setprio(0);                                    \
    BARRIER();                                                        \
  } while (0)

  // phase rows r0,r0+1 (r0 in {2,4,6}); POST_WAIT before the closing barrier
#define PHASE_R(dRd, r0, STAGE_STMT, POST_WAIT)                       \
  do {                                                                \
    aF[0] = smv[(dRd) + aI0 + (r0) * 128];                            \
    aF[1] = smv[(dRd) + aI1 + (r0) * 128];                            \
    aF[2] = smv[(dRd) + aI0 + (r0) * 128 + 128];                      \
    aF[3] = smv[(dRd) + aI1 + (r0) * 128 + 128];                      \
    STAGE_STMT;                                                       \
    BARRIER();                                                        \
    WAIT_LGKM0();                                                     \
    SCHED_FENCE();                                                    \
    __builtin_amdgcn_s_setprio(1);                                    \
    _Pragma("unroll")                                                 \
    for (int j = 0; j < 4; ++j) {                                     \
      acc[(r0)][j]     = MFMA16x16x32(aF[0], bF0[j], acc[(r0)][j]);   \
      acc[(r0)][j]     = MFMA16x16x32(aF[1], bF1[j], acc[(r0)][j]);   \
      acc[(r0) + 1][j] = MFMA16x16x32(aF[2], bF0[j], acc[(r0) + 1][j]); \
      acc[(r0) + 1][j] = MFMA16x16x32(aF[3], bF1[j], acc[(r0) + 1][j]); \
    }                                                                 \
    __builtin_amdgcn_s_setprio(0);                                    \
    POST_WAIT;                                                        \
    BARRIER();                                                        \
  } while (0)

  for (int s = 0; s < ns; ++s) {
    const bool nl = (s < ns - 1);
    // ---- phases 1-4: tile 2s (db0, read offset 0) ----
    PHASE_B(0, STAGE_A_H0(32768));                 // stage A(2s+1)-h0 -> db1
    PHASE_R(0, 2, STAGE_A_H1(32768), );            // stage A(2s+1)-h1 -> db1
    PHASE_R(0, 4, if (nl) STAGE_B_H0(0), );        // stage B(2s+2)-h0 -> db0
    PHASE_R(0, 6, if (nl) STAGE_B_H1(0),           // stage B(2s+2)-h1 -> db0
            if (nl) { WAIT_VM4(); } else { WAIT_VM0(); });
    // ---- phases 5-8: tile 2s+1 (db1, read offset 2048) ----
    PHASE_B(2048, if (nl) STAGE_A_H0(0));          // stage A(2s+2)-h0 -> db0
    PHASE_R(2048, 2, if (nl) STAGE_A_H1(0), );     // stage A(2s+2)-h1 -> db0
    PHASE_R(2048, 4, if (nl) STAGE_B_H0(32768), ); // stage B(2s+3)-h0 -> db1
    PHASE_R(2048, 6, if (nl) STAGE_B_H1(32768),    // stage B(2s+3)-h1 -> db1
            if (nl) WAIT_VM4());
  }

#undef PHASE_B
#undef PHASE_R
#undef STAGE_A_H0
#undef STAGE_A_H1
#undef STAGE_B_H0
#undef STAGE_B_H1

  // ---------------- epilogue: direct global stores ----------------
#pragma unroll
  for (int j = 0; j < 4; ++j) {
    const int col = col0 + wni * 64 + j * 16 + m;
    const float bj = bias[col];
#pragma unroll
    for (int i = 0; i < 8; ++i) {
      const int rowb = row0 + wmi * 128 + i * 16 + quad * 4;
#pragma unroll
      for (int r = 0; r < 4; ++r) {
        float v = acc[i][j][r] + bj;
        if (act == 1) {
          // tanh-form GELU (overflow-safe)
          float tt = 0.7978845608f * (v + 0.044715f * v * v * v);
          float e2 = __expf(-2.0f * fabsf(tt));
          float th = (1.0f - e2) / (1.0f + e2);
          th = tt < 0.0f ? -th : th;
          v = 0.5f * v * (1.0f + th);
        }
        C[(size_t)(rowb + r) * N + col] = __float2bfloat16(v);
      }
    }
  }
}

// ---------------------------------------------------------------- fused attention per (b,h)
// qkv fused: row stride 1536; q at col h*64, k at 512+h*64, v at 1024+h*64.
__global__ __launch_bounds__(384) void attn_fused(
    const __hip_bfloat16* __restrict__ qkv,
    const float* __restrict__ mat,
    float* __restrict__ scores,
    __hip_bfloat16* __restrict__ ctx) {
  __shared__ __align__(16) __hip_bfloat16 Ks[96 * 72];   // [l_k][d], pad 64->72
  __shared__ __align__(16) __hip_bfloat16 Vt[64 * 104];  // [d][l_k], pad 96->104
  __shared__ __align__(16) __hip_bfloat16 Ps[96 * 104];  // [l_q][l_k], pad 96->104
  const int bh = blockIdx.x;
  const int b = bh >> 3, h = bh & 7;
  const __hip_bfloat16* qb = qkv + (size_t)b * 96 * 1536 + h * 64;
  const __hip_bfloat16* kb = qb + 512;
  const __hip_bfloat16* vb = qb + 1024;
  const int tid = threadIdx.x;

  // stage K [96][64] -> Ks, 16B chunks
  for (int c = tid; c < 768; c += 384) {
    int row = c >> 3, c8 = (c & 7) * 8;
    *(short8*)&Ks[row * 72 + c8] = *(const short8*)(kb + (size_t)row * 1536 + c8);
  }
  // stage V transposed
  {
    int d = tid & 63;
    for (int l = tid >> 6; l < 96; l += 6) Vt[d * 104 + l] = vb[(size_t)l * 1536 + d];
  }
  __syncthreads();

  const int wave = tid >> 6, lane = tid & 63;
  const int quad = lane >> 4, m = lane & 15;

  // phase 1: S = Q K^T (16 rows per wave, N=96, K=64)
  short8 a0 = *(const short8*)(qb + (size_t)(wave * 16 + m) * 1536 + quad * 8);
  short8 a1 = *(const short8*)(qb + (size_t)(wave * 16 + m) * 1536 + 32 + quad * 8);
  floatx4 s[6];
  const size_t mbase = ((size_t)bh * 96 + wave * 16 + quad * 4) * 96 + m;
#pragma unroll
  for (int ct = 0; ct < 6; ++ct) {
    short8 b0 = *(const short8*)&Ks[(ct * 16 + m) * 72 + quad * 8];
    short8 b1 = *(const short8*)&Ks[(ct * 16 + m) * 72 + 32 + quad * 8];
    floatx4 accv = {};
    accv = MFMA16x16x32(a0, b0, accv);
    accv = MFMA16x16x32(a1, b1, accv);
#pragma unroll
    for (int r = 0; r < 4; ++r) {
      float sv = accv[r] * 0.125f * mat[mbase + (size_t)r * 96 + ct * 16];
      accv[r] = sv;
      scores[mbase + (size_t)r * 96 + ct * 16] = sv;
    }
    s[ct] = accv;
  }

  // softmax over each row
#pragma unroll
  for (int r = 0; r < 4; ++r) {
    float mx = s[0][r];
#pragma unroll
    for (int ct = 1; ct < 6; ++ct) mx = fmaxf(mx, s[ct][r]);
#pragma unroll
    for (int dd = 1; dd < 16; dd <<= 1) mx = fmaxf(mx, __shfl_xor(mx, dd, 64));
    float sum = 0.f;
#pragma unroll
    for (int ct = 0; ct < 6; ++ct) {
      float e = __expf(s[ct][r] - mx);
      s[ct][r] = e;
      sum += e;
    }
#pragma unroll
    for (int dd = 1; dd < 16; dd <<= 1) sum += __shfl_xor(sum, dd, 64);
    float inv = 1.0f / sum;
#pragma unroll
    for (int ct = 0; ct < 6; ++ct)
      Ps[(wave * 16 + quad * 4 + r) * 104 + ct * 16 + m] = __float2bfloat16(s[ct][r] * inv);
  }
  __syncthreads();

  // phase 2: O = P V  (K = 96, 3 k-steps of 32)
  floatx4 o[4] = {};
#pragma unroll
  for (int ks = 0; ks < 3; ++ks) {
    short8 pa = *(const short8*)&Ps[(wave * 16 + m) * 104 + ks * 32 + quad * 8];
#pragma unroll
    for (int ct = 0; ct < 4; ++ct) {
      short8 vv = *(const short8*)&Vt[(ct * 16 + m) * 104 + ks * 32 + quad * 8];
      o[ct] = MFMA16x16x32(pa, vv, o[ct]);
    }
  }
  __hip_bfloat16* cb = ctx + (size_t)b * 96 * 512 + h * 64;
#pragma unroll
  for (int ct = 0; ct < 4; ++ct)
#pragma unroll
    for (int r = 0; r < 4; ++r)
      cb[(size_t)(wave * 16 + quad * 4 + r) * 512 + ct * 16 + m] = __float2bfloat16(o[ct][r]);
}

// ---------------------------------------------------------------- residual + LayerNorm, one block per row (D=512)
template <typename RT, typename OT>
__global__ __launch_bounds__(256) void ln_res(
    const __hip_bfloat16* __restrict__ a, const RT* __restrict__ rsd,
    const float* __restrict__ g, const float* __restrict__ be,
    OT* __restrict__ out) {
  const int row = blockIdx.x;
  const int tid = threadIdx.x;
  const size_t base = (size_t)row * 512 + tid * 2;
  float x0 = __bfloat162float(a[base]) + to_f(rsd[base]);
  float x1 = __bfloat162float(a[base + 1]) + to_f(rsd[base + 1]);
  float s = x0 + x1, s2 = x0 * x0 + x1 * x1;
#pragma unroll
  for (int d = 1; d < 64; d <<= 1) {
    s += __shfl_xor(s, d, 64);
    s2 += __shfl_xor(s2, d, 64);
  }
  __shared__ float red[8];
  const int wave = tid >> 6, lane = tid & 63;
  if (lane == 0) {
    red[wave] = s;
    red[4 + wave] = s2;
  }
  __syncthreads();
  s = red[0] + red[1] + red[2] + red[3];
  s2 = red[4] + red[5] + red[6] + red[7];
  const float mean = s * (1.0f / 512.0f);
  const float var = s2 * (1.0f / 512.0f) - mean * mean;
  const float rstd = rsqrtf(var + 1e-5f);
  st_val(out + base, (x0 - mean) * rstd * g[tid * 2] + be[tid * 2]);
  st_val(out + base + 1, (x1 - mean) * rstd * g[tid * 2 + 1] + be[tid * 2 + 1]);
}

// ---------------------------------------------------------------- launch
extern "C" void kernel_launch(void* const* d_in, const int* in_sizes, int n_in,
                              void* d_out, int out_size, void* d_ws, size_t ws_size,
                              hipStream_t stream) {
  (void)in_sizes; (void)n_in; (void)out_size; (void)ws_size;
  typedef const float* cf;
  typedef __hip_bfloat16* bf;
  cf src = (cf)d_in[0];
  cf Wq = (cf)d_in[1];  cf bq = (cf)d_in[2];
  cf Wk = (cf)d_in[3];  cf bk = (cf)d_in[4];
  cf Wv = (cf)d_in[5];  cf bv = (cf)d_in[6];
  cf mat = (cf)d_in[7];
  cf Wo = (cf)d_in[8];  cf bo = (cf)d_in[9];
  cf g1 = (cf)d_in[10]; cf be1 = (cf)d_in[11];
  cf W1 = (cf)d_in[12]; cf b1 = (cf)d_in[13];
  cf W2 = (cf)d_in[14]; cf b2 = (cf)d_in[15];
  cf g2 = (cf)d_in[16]; cf be2 = (cf)d_in[17];

  char* ws = (char*)d_ws;
  const size_t SZ = (size_t)24576 * 512 * 2;  // 25,165,824 B
  bf qkv = (bf)(ws);                  // [24576][1536] bf16 = 3*SZ
  bf ctx = (bf)(ws + 3 * SZ);
  bf hb  = (bf)(ws);                  // FFN hidden [24576][2048] = 4*SZ; qkv+ctx dead by then
  bf srcb = (bf)(ws + 4 * SZ);        // dead after qkv-gemm
  bf tmp = (bf)(ws + 4 * SZ);         // wo out -> ln1; later ffn2 out -> ln2
  bf xb  = (bf)(ws + 5 * SZ);         // post-LN1 x
  char* wt = ws + 6 * SZ;
  bf WqkvT = (bf)(wt);                          // [1536][512] bf16
  bf WoT = (bf)(wt + 1572864);
  bf W1T = (bf)(wt + 1572864 + 524288);         // [2048][512]
  bf W2T = (bf)(wt + 1572864 + 524288 + 2097152);  // [512][2048]
  float* bqkv = (float*)(wt + 1572864 + 524288 + 2097152 + 2097152);

  float* yout = (float*)d_out;
  float* scout = (float*)d_out + 12582912;  // scores after y

  cvt_f32_bf16<<<12288, 256, 0, stream>>>((const float4*)src, (ushort*)srcb);
  concat3<<<6, 256, 0, stream>>>(bq, bk, bv, bqkv);

  dim3 tb(32, 8);
  transpose_cvt<<<dim3(16, 16), tb, 0, stream>>>(Wq, WqkvT, 512, 512);
  transpose_cvt<<<dim3(16, 16), tb, 0, stream>>>(Wk, WqkvT + 512 * 512, 512, 512);
  transpose_cvt<<<dim3(16, 16), tb, 0, stream>>>(Wv, WqkvT + 1024 * 512, 512, 512);
  transpose_cvt<<<dim3(16, 16), tb, 0, stream>>>(Wo, WoT, 512, 512);
  transpose_cvt<<<dim3(64, 16), tb, 0, stream>>>(W1, W1T, 512, 2048);
  transpose_cvt<<<dim3(16, 64), tb, 0, stream>>>(W2, W2T, 2048, 512);

  // 256x256-tile 8-phase GEMMs; tiles_x = N/256, grid = (M/256)*(N/256), all %8==0
  gemm256<<<576, 512, 0, stream>>>(srcb, WqkvT, bqkv, qkv, 24576, 1536, 512, 0, 6);

  attn_fused<<<2048, 384, 0, stream>>>(qkv, mat, scout, ctx);

  gemm256<<<192, 512, 0, stream>>>(ctx, WoT, bo, tmp, 24576, 512, 512, 0, 2);
  ln_res<float, __hip_bfloat16><<<24576, 256, 0, stream>>>(tmp, src, g1, be1, xb);
  gemm256<<<768, 512, 0, stream>>>(xb, W1T, b1, hb, 24576, 2048, 512, 1, 8);
  gemm256<<<192, 512, 0, stream>>>(hb, W2T, b2, tmp, 24576, 512, 2048, 0, 2);
  ln_res<__hip_bfloat16, float><<<24576, 256, 0, stream>>>(tmp, xb, g2, be2, yout);
}

// Round 7
// 551.810 us; speedup vs baseline: 1.1303x; 1.0783x over previous
//
#include <hip/hip_runtime.h>
#include <hip/hip_bf16.h>
#include <math.h>

typedef __attribute__((ext_vector_type(8))) short short8;
typedef __attribute__((ext_vector_type(4))) float floatx4;

// ---------------------------------------------------------------- helpers
__device__ __forceinline__ void load_lds16(const void* g, void* l) {
  __builtin_amdgcn_global_load_lds(
      (__attribute__((address_space(1))) void*)(g),
      (__attribute__((address_space(3))) void*)(l), 16, 0, 0);
}

#define MFMA16x16x32(a, b, c) __builtin_amdgcn_mfma_f32_16x16x32_bf16((a), (b), (c), 0, 0, 0)

__device__ __forceinline__ float to_f(float x) { return x; }
__device__ __forceinline__ float to_f(__hip_bfloat16 x) { return __bfloat162float(x); }
__device__ __forceinline__ void st_val(float* p, float v) { *p = v; }
__device__ __forceinline__ void st_val(__hip_bfloat16* p, float v) { *p = __float2bfloat16(v); }

// ---------------------------------------------------------------- fp32 -> bf16 elementwise (src)
__global__ __launch_bounds__(256) void cvt_f32_bf16(const float4* __restrict__ in,
                                                    ushort* __restrict__ out) {
  int i = blockIdx.x * 256 + threadIdx.x;
  float4 v = in[i];
  ushort4 o;
  __hip_bfloat16 b0 = __float2bfloat16(v.x);
  __hip_bfloat16 b1 = __float2bfloat16(v.y);
  __hip_bfloat16 b2 = __float2bfloat16(v.z);
  __hip_bfloat16 b3 = __float2bfloat16(v.w);
  o.x = *(ushort*)&b0; o.y = *(ushort*)&b1; o.z = *(ushort*)&b2; o.w = *(ushort*)&b3;
  *(ushort4*)(out + 4 * i) = o;
}

// ---------------------------------------------------------------- concat 3 bias vectors (512 each)
__global__ void concat3(const float* __restrict__ a, const float* __restrict__ b,
                        const float* __restrict__ c, float* __restrict__ o) {
  int i = blockIdx.x * 256 + threadIdx.x;  // 0..1535
  o[i] = i < 512 ? a[i] : (i < 1024 ? b[i - 512] : c[i - 1024]);
}

// ---------------------------------------------------------------- fp32 weights -> bf16 transposed
__global__ void transpose_cvt(const float* __restrict__ in,
                              __hip_bfloat16* __restrict__ out, int R, int C) {
  __shared__ __hip_bfloat16 tile[32][33];
  int bx = blockIdx.x * 32, by = blockIdx.y * 32;
  int tx = threadIdx.x, ty = threadIdx.y;  // (32,8)
  for (int i = ty; i < 32; i += 8)
    tile[i][tx] = __float2bfloat16(in[(size_t)(by + i) * C + bx + tx]);
  __syncthreads();
  for (int i = ty; i < 32; i += 8) out[(size_t)(bx + i) * R + by + tx] = tile[tx][i];
}

// ---------------------------------------------------------------- GEMM: C[M,N] = A[M,K] @ BT[N,K]^T + bias, opt GELU
// m97-class structure (learn_hip: 912 TF @4096^3): 128x128 tile, BK=64,
// 4 waves (2M x 2N), per-wave 64x64 (acc[4][4] -> 64 AGPR), single 32 KB LDS
// buffer, 2 barriers per K-tile, NO explicit pipelining — overlap comes from
// 3 independent blocks/CU (reg-limited; LDS would allow 5). Compiler inserts
// vmcnt/lgkm waits at __syncthreads (known-good m97 behavior).
// LDS swizzle (counter-verified r4/r6: SQ_LDS_BANK_CONFLICT = 0): 16-B chunk c
// of each 128-B row holds global chunk c^(row&7); stage = linear
// global_load_lds dest + pre-swizzled GLOBAL source chunk (l&7)^(l>>3);
// read chunk' = (quad+4*kk)^(m&7).
// LDS: A [128 rows][64 kk] bf16 = 16 KB @0; B same @16384. Total 32 KB.
__global__ __launch_bounds__(256, 3) void gemm128(
    const __hip_bfloat16* __restrict__ A,
    const __hip_bfloat16* __restrict__ BT,
    const float* __restrict__ bias,
    __hip_bfloat16* __restrict__ C,
    int N, int K, int act, int tiles_x) {
  __shared__ __align__(16) short8 smv[2048];  // 32 KB
  char* smc = (char*)smv;
  const int tid = threadIdx.x;
  const int wave = tid >> 6, lane = tid & 63;
  const int quad = lane >> 4, m = lane & 15;
  const int wmi = wave >> 1, wni = wave & 1;
  // bijective XCD-chunked swizzle (grid % 8 == 0 for all call sites)
  const int nwg = gridDim.x;
  const int wg = (blockIdx.x & 7) * (nwg >> 3) + (blockIdx.x >> 3);
  const int row0 = (wg / tiles_x) * 128;
  const int col0 = (wg % tiles_x) * 128;
  const int nt = K >> 6;

  // ---- staging (pre-swizzled source chunk; linear LDS dest) ----
  // chunk c = r*4+wave covers rows c*8+(lane>>3), row&7 = lane>>3
  const int colb = (((lane & 7) ^ (lane >> 3)) << 4);
  const int rbase = wave * 8 + (lane >> 3);
  const char* pA[4];
  const char* pB[4];
  char* dA[4];
  char* dB[4];
#pragma unroll
  for (int r = 0; r < 4; ++r) {
    pA[r] = (const char*)(A + (size_t)(row0 + rbase + r * 32) * K) + colb;
    pB[r] = (const char*)(BT + (size_t)(col0 + rbase + r * 32) * K) + colb;
    dA[r] = smc + (r * 4 + wave) * 1024;
    dB[r] = smc + 16384 + (r * 4 + wave) * 1024;
  }

  // ---- fragment read indices (16-B units; typed LDS -> ds_read_b128) ----
  const int rc0 = m * 8 + ((quad)     ^ (m & 7));
  const int rc1 = m * 8 + ((quad + 4) ^ (m & 7));
  const int aB = wmi * 512;         // A rows wmi*64..+63
  const int bB = 1024 + wni * 512;  // B cols wni*64..+63

  floatx4 acc[4][4] = {};

  for (int t = 0; t < nt; ++t) {
#pragma unroll
    for (int r = 0; r < 4; ++r) { load_lds16(pA[r], dA[r]); pA[r] += 128; }
#pragma unroll
    for (int r = 0; r < 4; ++r) { load_lds16(pB[r], dB[r]); pB[r] += 128; }
    __syncthreads();  // compiler drains vmcnt(0) here (m97 behavior)
    short8 aF[4], bF[4];
    // kk0
#pragma unroll
    for (int i = 0; i < 4; ++i) aF[i] = smv[aB + i * 128 + rc0];
#pragma unroll
    for (int j = 0; j < 4; ++j) bF[j] = smv[bB + j * 128 + rc0];
#pragma unroll
    for (int i = 0; i < 4; ++i)
#pragma unroll
      for (int j = 0; j < 4; ++j) acc[i][j] = MFMA16x16x32(aF[i], bF[j], acc[i][j]);
    // kk1
#pragma unroll
    for (int i = 0; i < 4; ++i) aF[i] = smv[aB + i * 128 + rc1];
#pragma unroll
    for (int j = 0; j < 4; ++j) bF[j] = smv[bB + j * 128 + rc1];
#pragma unroll
    for (int i = 0; i < 4; ++i)
#pragma unroll
      for (int j = 0; j < 4; ++j) acc[i][j] = MFMA16x16x32(aF[i], bF[j], acc[i][j]);
    __syncthreads();
  }

  // ---------------- epilogue: direct global stores ----------------
#pragma unroll
  for (int j = 0; j < 4; ++j) {
    const int col = col0 + wni * 64 + j * 16 + m;
    const float bj = bias[col];
#pragma unroll
    for (int i = 0; i < 4; ++i) {
      const int rowb = row0 + wmi * 64 + i * 16 + quad * 4;
#pragma unroll
      for (int r = 0; r < 4; ++r) {
        float v = acc[i][j][r] + bj;
        if (act == 1) {
          // tanh-form GELU (overflow-safe)
          float tt = 0.7978845608f * (v + 0.044715f * v * v * v);
          float e2 = __expf(-2.0f * fabsf(tt));
          float th = (1.0f - e2) / (1.0f + e2);
          th = tt < 0.0f ? -th : th;
          v = 0.5f * v * (1.0f + th);
        }
        C[(size_t)(rowb + r) * N + col] = __float2bfloat16(v);
      }
    }
  }
}

// ---------------------------------------------------------------- fused attention per (b,h)
// qkv fused: row stride 1536; q at col h*64, k at 512+h*64, v at 1024+h*64.
__global__ __launch_bounds__(384) void attn_fused(
    const __hip_bfloat16* __restrict__ qkv,
    const float* __restrict__ mat,
    float* __restrict__ scores,
    __hip_bfloat16* __restrict__ ctx) {
  __shared__ __align__(16) __hip_bfloat16 Ks[96 * 72];   // [l_k][d], pad 64->72
  __shared__ __align__(16) __hip_bfloat16 Vt[64 * 104];  // [d][l_k], pad 96->104
  __shared__ __align__(16) __hip_bfloat16 Ps[96 * 104];  // [l_q][l_k], pad 96->104
  const int bh = blockIdx.x;
  const int b = bh >> 3, h = bh & 7;
  const __hip_bfloat16* qb = qkv + (size_t)b * 96 * 1536 + h * 64;
  const __hip_bfloat16* kb = qb + 512;
  const __hip_bfloat16* vb = qb + 1024;
  const int tid = threadIdx.x;

  // stage K [96][64] -> Ks, 16B chunks
  for (int c = tid; c < 768; c += 384) {
    int row = c >> 3, c8 = (c & 7) * 8;
    *(short8*)&Ks[row * 72 + c8] = *(const short8*)(kb + (size_t)row * 1536 + c8);
  }
  // stage V transposed
  {
    int d = tid & 63;
    for (int l = tid >> 6; l < 96; l += 6) Vt[d * 104 + l] = vb[(size_t)l * 1536 + d];
  }
  __syncthreads();

  const int wave = tid >> 6, lane = tid & 63;
  const int quad = lane >> 4, m = lane & 15;

  // phase 1: S = Q K^T (16 rows per wave, N=96, K=64)
  short8 a0 = *(const short8*)(qb + (size_t)(wave * 16 + m) * 1536 + quad * 8);
  short8 a1 = *(const short8*)(qb + (size_t)(wave * 16 + m) * 1536 + 32 + quad * 8);
  floatx4 s[6];
  const size_t mbase = ((size_t)bh * 96 + wave * 16 + quad * 4) * 96 + m;
#pragma unroll
  for (int ct = 0; ct < 6; ++ct) {
    short8 b0 = *(const short8*)&Ks[(ct * 16 + m) * 72 + quad * 8];
    short8 b1 = *(const short8*)&Ks[(ct * 16 + m) * 72 + 32 + quad * 8];
    floatx4 accv = {};
    accv = MFMA16x16x32(a0, b0, accv);
    accv = MFMA16x16x32(a1, b1, accv);
#pragma unroll
    for (int r = 0; r < 4; ++r) {
      float sv = accv[r] * 0.125f * mat[mbase + (size_t)r * 96 + ct * 16];
      accv[r] = sv;
      scores[mbase + (size_t)r * 96 + ct * 16] = sv;
    }
    s[ct] = accv;
  }

  // softmax over each row
#pragma unroll
  for (int r = 0; r < 4; ++r) {
    float mx = s[0][r];
#pragma unroll
    for (int ct = 1; ct < 6; ++ct) mx = fmaxf(mx, s[ct][r]);
#pragma unroll
    for (int dd = 1; dd < 16; dd <<= 1) mx = fmaxf(mx, __shfl_xor(mx, dd, 64));
    float sum = 0.f;
#pragma unroll
    for (int ct = 0; ct < 6; ++ct) {
      float e = __expf(s[ct][r] - mx);
      s[ct][r] = e;
      sum += e;
    }
#pragma unroll
    for (int dd = 1; dd < 16; dd <<= 1) sum += __shfl_xor(sum, dd, 64);
    float inv = 1.0f / sum;
#pragma unroll
    for (int ct = 0; ct < 6; ++ct)
      Ps[(wave * 16 + quad * 4 + r) * 104 + ct * 16 + m] = __float2bfloat16(s[ct][r] * inv);
  }
  __syncthreads();

  // phase 2: O = P V  (K = 96, 3 k-steps of 32)
  floatx4 o[4] = {};
#pragma unroll
  for (int ks = 0; ks < 3; ++ks) {
    short8 pa = *(const short8*)&Ps[(wave * 16 + m) * 104 + ks * 32 + quad * 8];
#pragma unroll
    for (int ct = 0; ct < 4; ++ct) {
      short8 vv = *(const short8*)&Vt[(ct * 16 + m) * 104 + ks * 32 + quad * 8];
      o[ct] = MFMA16x16x32(pa, vv, o[ct]);
    }
  }
  __hip_bfloat16* cb = ctx + (size_t)b * 96 * 512 + h * 64;
#pragma unroll
  for (int ct = 0; ct < 4; ++ct)
#pragma unroll
    for (int r = 0; r < 4; ++r)
      cb[(size_t)(wave * 16 + quad * 4 + r) * 512 + ct * 16 + m] = __float2bfloat16(o[ct][r]);
}

// ---------------------------------------------------------------- residual + LayerNorm, one block per row (D=512)
template <typename RT, typename OT>
__global__ __launch_bounds__(256) void ln_res(
    const __hip_bfloat16* __restrict__ a, const RT* __restrict__ rsd,
    const float* __restrict__ g, const float* __restrict__ be,
    OT* __restrict__ out) {
  const int row = blockIdx.x;
  const int tid = threadIdx.x;
  const size_t base = (size_t)row * 512 + tid * 2;
  float x0 = __bfloat162float(a[base]) + to_f(rsd[base]);
  float x1 = __bfloat162float(a[base + 1]) + to_f(rsd[base + 1]);
  float s = x0 + x1, s2 = x0 * x0 + x1 * x1;
#pragma unroll
  for (int d = 1; d < 64; d <<= 1) {
    s += __shfl_xor(s, d, 64);
    s2 += __shfl_xor(s2, d, 64);
  }
  __shared__ float red[8];
  const int wave = tid >> 6, lane = tid & 63;
  if (lane == 0) {
    red[wave] = s;
    red[4 + wave] = s2;
  }
  __syncthreads();
  s = red[0] + red[1] + red[2] + red[3];
  s2 = red[4] + red[5] + red[6] + red[7];
  const float mean = s * (1.0f / 512.0f);
  const float var = s2 * (1.0f / 512.0f) - mean * mean;
  const float rstd = rsqrtf(var + 1e-5f);
  st_val(out + base, (x0 - mean) * rstd * g[tid * 2] + be[tid * 2]);
  st_val(out + base + 1, (x1 - mean) * rstd * g[tid * 2 + 1] + be[tid * 2 + 1]);
}

// ---------------------------------------------------------------- launch
extern "C" void kernel_launch(void* const* d_in, const int* in_sizes, int n_in,
                              void* d_out, int out_size, void* d_ws, size_t ws_size,
                              hipStream_t stream) {
  (void)in_sizes; (void)n_in; (void)out_size; (void)ws_size;
  typedef const float* cf;
  typedef __hip_bfloat16* bf;
  cf src = (cf)d_in[0];
  cf Wq = (cf)d_in[1];  cf bq = (cf)d_in[2];
  cf Wk = (cf)d_in[3];  cf bk = (cf)d_in[4];
  cf Wv = (cf)d_in[5];  cf bv = (cf)d_in[6];
  cf mat = (cf)d_in[7];
  cf Wo = (cf)d_in[8];  cf bo = (cf)d_in[9];
  cf g1 = (cf)d_in[10]; cf be1 = (cf)d_in[11];
  cf W1 = (cf)d_in[12]; cf b1 = (cf)d_in[13];
  cf W2 = (cf)d_in[14]; cf b2 = (cf)d_in[15];
  cf g2 = (cf)d_in[16]; cf be2 = (cf)d_in[17];

  char* ws = (char*)d_ws;
  const size_t SZ = (size_t)24576 * 512 * 2;  // 25,165,824 B
  bf qkv = (bf)(ws);                  // [24576][1536] bf16 = 3*SZ
  bf ctx = (bf)(ws + 3 * SZ);
  bf hb  = (bf)(ws);                  // FFN hidden [24576][2048] = 4*SZ; qkv+ctx dead by then
  bf srcb = (bf)(ws + 4 * SZ);        // dead after qkv-gemm
  bf tmp = (bf)(ws + 4 * SZ);         // wo out -> ln1; later ffn2 out -> ln2
  bf xb  = (bf)(ws + 5 * SZ);         // post-LN1 x
  char* wt = ws + 6 * SZ;
  bf WqkvT = (bf)(wt);                          // [1536][512] bf16
  bf WoT = (bf)(wt + 1572864);
  bf W1T = (bf)(wt + 1572864 + 524288);         // [2048][512]
  bf W2T = (bf)(wt + 1572864 + 524288 + 2097152);  // [512][2048]
  float* bqkv = (float*)(wt + 1572864 + 524288 + 2097152 + 2097152);

  float* yout = (float*)d_out;
  float* scout = (float*)d_out + 12582912;  // scores after y

  cvt_f32_bf16<<<12288, 256, 0, stream>>>((const float4*)src, (ushort*)srcb);
  concat3<<<6, 256, 0, stream>>>(bq, bk, bv, bqkv);

  dim3 tb(32, 8);
  transpose_cvt<<<dim3(16, 16), tb, 0, stream>>>(Wq, WqkvT, 512, 512);
  transpose_cvt<<<dim3(16, 16), tb, 0, stream>>>(Wk, WqkvT + 512 * 512, 512, 512);
  transpose_cvt<<<dim3(16, 16), tb, 0, stream>>>(Wv, WqkvT + 1024 * 512, 512, 512);
  transpose_cvt<<<dim3(16, 16), tb, 0, stream>>>(Wo, WoT, 512, 512);
  transpose_cvt<<<dim3(64, 16), tb, 0, stream>>>(W1, W1T, 512, 2048);
  transpose_cvt<<<dim3(16, 64), tb, 0, stream>>>(W2, W2T, 2048, 512);

  // 128x128-tile m97-style GEMMs; tiles_x = N/128, grid = (M/128)*(N/128), all %8==0
  gemm128<<<2304, 256, 0, stream>>>(srcb, WqkvT, bqkv, qkv, 1536, 512, 0, 12);

  attn_fused<<<2048, 384, 0, stream>>>(qkv, mat, scout, ctx);

  gemm128<<<768, 256, 0, stream>>>(ctx, WoT, bo, tmp, 512, 512, 0, 4);
  ln_res<float, __hip_bfloat16><<<24576, 256, 0, stream>>>(tmp, src, g1, be1, xb);
  gemm128<<<3072, 256, 0, stream>>>(xb, W1T, b1, hb, 2048, 512, 1, 16);
  gemm128<<<768, 256, 0, stream>>>(hb, W2T, b2, tmp, 512, 2048, 0, 4);
  ln_res<__hip_bfloat16, float><<<24576, 256, 0, stream>>>(tmp, xb, g2, be2, yout);
}

// Round 9
// 536.325 us; speedup vs baseline: 1.1629x; 1.0289x over previous
//
#include <hip/hip_runtime.h>
#include <hip/hip_bf16.h>
#include <math.h>

typedef __attribute__((ext_vector_type(8))) short short8;
typedef __attribute__((ext_vector_type(4))) float floatx4;

// ---------------------------------------------------------------- helpers
__device__ __forceinline__ void load_lds16(const void* g, void* l) {
  __builtin_amdgcn_global_load_lds(
      (__attribute__((address_space(1))) void*)(g),
      (__attribute__((address_space(3))) void*)(l), 16, 0, 0);
}

#define MFMA16x16x32(a, b, c) __builtin_amdgcn_mfma_f32_16x16x32_bf16((a), (b), (c), 0, 0, 0)

__device__ __forceinline__ float to_f(float x) { return x; }
__device__ __forceinline__ float to_f(__hip_bfloat16 x) { return __bfloat162float(x); }

// vectorized 8-element load/store (G13: never scalar bf16)
__device__ __forceinline__ void load8f(const float* p, float* x) {
  float4 a = *(const float4*)p, b = *(const float4*)(p + 4);
  x[0] = a.x; x[1] = a.y; x[2] = a.z; x[3] = a.w;
  x[4] = b.x; x[5] = b.y; x[6] = b.z; x[7] = b.w;
}
__device__ __forceinline__ void load8f(const __hip_bfloat16* p, float* x) {
  short8 v = *(const short8*)p;
#pragma unroll
  for (int k = 0; k < 8; ++k) {
    ushort u = (ushort)v[k];
    __hip_bfloat16 h;
    *(ushort*)&h = u;
    x[k] = __bfloat162float(h);
  }
}
__device__ __forceinline__ void store8f(float* p, const float* x) {
  *(float4*)p = make_float4(x[0], x[1], x[2], x[3]);
  *(float4*)(p + 4) = make_float4(x[4], x[5], x[6], x[7]);
}
__device__ __forceinline__ void store8f(__hip_bfloat16* p, const float* x) {
  short8 o;
#pragma unroll
  for (int k = 0; k < 8; ++k) {
    __hip_bfloat16 h = __float2bfloat16(x[k]);
    o[k] = *(ushort*)&h;
  }
  *(short8*)p = o;
}

// ---------------------------------------------------------------- fp32 -> bf16 elementwise (src)
__global__ __launch_bounds__(256) void cvt_f32_bf16(const float4* __restrict__ in,
                                                    ushort* __restrict__ out) {
  int i = blockIdx.x * 256 + threadIdx.x;
  float4 v = in[i];
  ushort4 o;
  __hip_bfloat16 b0 = __float2bfloat16(v.x);
  __hip_bfloat16 b1 = __float2bfloat16(v.y);
  __hip_bfloat16 b2 = __float2bfloat16(v.z);
  __hip_bfloat16 b3 = __float2bfloat16(v.w);
  o.x = *(ushort*)&b0; o.y = *(ushort*)&b1; o.z = *(ushort*)&b2; o.w = *(ushort*)&b3;
  *(ushort4*)(out + 4 * i) = o;
}

// ---------------------------------------------------------------- concat 3 bias vectors (512 each)
__global__ void concat3(const float* __restrict__ a, const float* __restrict__ b,
                        const float* __restrict__ c, float* __restrict__ o) {
  int i = blockIdx.x * 256 + threadIdx.x;  // 0..1535
  o[i] = i < 512 ? a[i] : (i < 1024 ? b[i - 512] : c[i - 1024]);
}

// ---------------------------------------------------------------- fp32 weights -> bf16 transposed
__global__ void transpose_cvt(const float* __restrict__ in,
                              __hip_bfloat16* __restrict__ out, int R, int C) {
  __shared__ __hip_bfloat16 tile[32][33];
  int bx = blockIdx.x * 32, by = blockIdx.y * 32;
  int tx = threadIdx.x, ty = threadIdx.y;  // (32,8)
  for (int i = ty; i < 32; i += 8)
    tile[i][tx] = __float2bfloat16(in[(size_t)(by + i) * C + bx + tx]);
  __syncthreads();
  for (int i = ty; i < 32; i += 8) out[(size_t)(bx + i) * R + by + tx] = tile[tx][i];
}

// ---------------------------------------------------------------- GEMM: C[M,N] = A[M,K] @ BT[N,K]^T + bias, opt GELU
// m97-class structure (r7-verified: 605 TF FFN1, conflicts=0): 128x128 tile,
// BK=64, 4 waves (2M x 2N), acc[4][4] (64 AGPR), single 32 KB LDS buffer,
// 2 barriers/K-tile; overlap from 4 independent blocks/CU (128 reg/lane).
// LDS swizzle (counter-verified): 16-B chunk c of each 128-B row holds global
// chunk c^(row&7); stage = linear global_load_lds dest + pre-swizzled GLOBAL
// source chunk (l&7)^(l>>3); read chunk' = (quad+4*kk)^(m&7).
// r8: LDS-staged epilogue — acc -> bf16 LDS tile (chunk-XOR rL&15, verified
// round-trip; read 2-way free, write ~2-way) -> 256-B-contiguous dwordx4
// stores. Kills the ~1.8x write-sector amplification of 2-B scattered stores.
__global__ __launch_bounds__(256, 4) void gemm128(
    const __hip_bfloat16* __restrict__ A,
    const __hip_bfloat16* __restrict__ BT,
    const float* __restrict__ bias,
    __hip_bfloat16* __restrict__ C,
    int N, int K, int act, int tiles_x) {
  __shared__ __align__(16) short8 smv[2048];  // 32 KB
  char* smc = (char*)smv;
  const int tid = threadIdx.x;
  const int wave = tid >> 6, lane = tid & 63;
  const int quad = lane >> 4, m = lane & 15;
  const int wmi = wave >> 1, wni = wave & 1;
  // bijective XCD-chunked swizzle (grid % 8 == 0 for all call sites)
  const int nwg = gridDim.x;
  const int wg = (blockIdx.x & 7) * (nwg >> 3) + (blockIdx.x >> 3);
  const int row0 = (wg / tiles_x) * 128;
  const int col0 = (wg % tiles_x) * 128;
  const int nt = K >> 6;

  // ---- staging (pre-swizzled source chunk; linear LDS dest) ----
  const int colb = (((lane & 7) ^ (lane >> 3)) << 4);
  const int rbase = wave * 8 + (lane >> 3);
  const char* pA[4];
  const char* pB[4];
  char* dA[4];
  char* dB[4];
#pragma unroll
  for (int r = 0; r < 4; ++r) {
    pA[r] = (const char*)(A + (size_t)(row0 + rbase + r * 32) * K) + colb;
    pB[r] = (const char*)(BT + (size_t)(col0 + rbase + r * 32) * K) + colb;
    dA[r] = smc + (r * 4 + wave) * 1024;
    dB[r] = smc + 16384 + (r * 4 + wave) * 1024;
  }

  // ---- fragment read indices (16-B units; typed LDS -> ds_read_b128) ----
  const int rc0 = m * 8 + ((quad)     ^ (m & 7));
  const int rc1 = m * 8 + ((quad + 4) ^ (m & 7));
  const int aB = wmi * 512;         // A rows wmi*64..+63
  const int bB = 1024 + wni * 512;  // B cols wni*64..+63

  floatx4 acc[4][4] = {};

  for (int t = 0; t < nt; ++t) {
#pragma unroll
    for (int r = 0; r < 4; ++r) { load_lds16(pA[r], dA[r]); pA[r] += 128; }
#pragma unroll
    for (int r = 0; r < 4; ++r) { load_lds16(pB[r], dB[r]); pB[r] += 128; }
    __syncthreads();  // compiler drains vmcnt(0) here (m97 behavior)
    short8 aF[4], bF[4];
    // kk0
#pragma unroll
    for (int i = 0; i < 4; ++i) aF[i] = smv[aB + i * 128 + rc0];
#pragma unroll
    for (int j = 0; j < 4; ++j) bF[j] = smv[bB + j * 128 + rc0];
#pragma unroll
    for (int i = 0; i < 4; ++i)
#pragma unroll
      for (int j = 0; j < 4; ++j) acc[i][j] = MFMA16x16x32(aF[i], bF[j], acc[i][j]);
    // kk1
#pragma unroll
    for (int i = 0; i < 4; ++i) aF[i] = smv[aB + i * 128 + rc1];
#pragma unroll
    for (int j = 0; j < 4; ++j) bF[j] = smv[bB + j * 128 + rc1];
#pragma unroll
    for (int i = 0; i < 4; ++i)
#pragma unroll
      for (int j = 0; j < 4; ++j) acc[i][j] = MFMA16x16x32(aF[i], bF[j], acc[i][j]);
    __syncthreads();
  }

  // ---------------- epilogue: acc -> swizzled bf16 LDS tile -> coalesced stores
  // LDS tile [128 rows][256 B]; byte = rL*256 + ((colL*2) ^ ((rL&15)<<4)).
  // Round-trip exact (swz bits 4-7; chunk-internal bits 0-3 unaffected).
  // Read: 16 lanes sweep all 16 chunks of a row (XOR permutes) -> 2-way free.
  // Global: 256 B contiguous per 16 lanes.
  {
    ushort* se = (ushort*)smv;
#pragma unroll
    for (int j = 0; j < 4; ++j) {
      const int colL = wni * 64 + j * 16 + m;
      const float bj = bias[col0 + colL];
#pragma unroll
      for (int i = 0; i < 4; ++i) {
        const int rowL = wmi * 64 + i * 16 + quad * 4;
#pragma unroll
        for (int r = 0; r < 4; ++r) {
          float v = acc[i][j][r] + bj;
          if (act == 1) {
            // tanh-form GELU (overflow-safe)
            float tt = 0.7978845608f * (v + 0.044715f * v * v * v);
            float e2 = __expf(-2.0f * fabsf(tt));
            float th = (1.0f - e2) / (1.0f + e2);
            th = tt < 0.0f ? -th : th;
            v = 0.5f * v * (1.0f + th);
          }
          const int rL = rowL + r;
          const int byte = rL * 256 + ((colL * 2) ^ ((rL & 15) << 4));
          __hip_bfloat16 bv = __float2bfloat16(v);
          se[byte >> 1] = *(ushort*)&bv;
        }
      }
    }
    __syncthreads();
#pragma unroll
    for (int p = 0; p < 8; ++p) {
      const int rL = p * 16 + (tid >> 4);
      const int c = tid & 15;
      const int byte = rL * 256 + ((c * 16) ^ ((rL & 15) << 4));
      *(short8*)(C + (size_t)(row0 + rL) * N + col0 + c * 8) =
          *(const short8*)(smc + byte);
    }
  }
}

// ---------------------------------------------------------------- fused attention per (b,h)
// qkv fused: row stride 1536; q at col h*64, k at 512+h*64, v at 1024+h*64.
__global__ __launch_bounds__(384) void attn_fused(
    const __hip_bfloat16* __restrict__ qkv,
    const float* __restrict__ mat,
    float* __restrict__ scores,
    __hip_bfloat16* __restrict__ ctx) {
  __shared__ __align__(16) __hip_bfloat16 Ks[96 * 72];   // [l_k][d], pad 64->72
  __shared__ __align__(16) __hip_bfloat16 Vt[64 * 104];  // [d][l_k], pad 96->104
  __shared__ __align__(16) __hip_bfloat16 Ps[96 * 104];  // [l_q][l_k], pad 96->104
  const int bh = blockIdx.x;
  const int b = bh >> 3, h = bh & 7;
  const __hip_bfloat16* qb = qkv + (size_t)b * 96 * 1536 + h * 64;
  const __hip_bfloat16* kb = qb + 512;
  const __hip_bfloat16* vb = qb + 1024;
  const int tid = threadIdx.x;

  // stage K [96][64] -> Ks, 16B chunks
  for (int c = tid; c < 768; c += 384) {
    int row = c >> 3, c8 = (c & 7) * 8;
    *(short8*)&Ks[row * 72 + c8] = *(const short8*)(kb + (size_t)row * 1536 + c8);
  }
  // stage V transposed
  {
    int d = tid & 63;
    for (int l = tid >> 6; l < 96; l += 6) Vt[d * 104 + l] = vb[(size_t)l * 1536 + d];
  }
  __syncthreads();

  const int wave = tid >> 6, lane = tid & 63;
  const int quad = lane >> 4, m = lane & 15;

  // phase 1: S = Q K^T (16 rows per wave, N=96, K=64)
  short8 a0 = *(const short8*)(qb + (size_t)(wave * 16 + m) * 1536 + quad * 8);
  short8 a1 = *(const short8*)(qb + (size_t)(wave * 16 + m) * 1536 + 32 + quad * 8);
  floatx4 s[6];
  const size_t mbase = ((size_t)bh * 96 + wave * 16 + quad * 4) * 96 + m;
#pragma unroll
  for (int ct = 0; ct < 6; ++ct) {
    short8 b0 = *(const short8*)&Ks[(ct * 16 + m) * 72 + quad * 8];
    short8 b1 = *(const short8*)&Ks[(ct * 16 + m) * 72 + 32 + quad * 8];
    floatx4 accv = {};
    accv = MFMA16x16x32(a0, b0, accv);
    accv = MFMA16x16x32(a1, b1, accv);
#pragma unroll
    for (int r = 0; r < 4; ++r) {
      float sv = accv[r] * 0.125f * mat[mbase + (size_t)r * 96 + ct * 16];
      accv[r] = sv;
      scores[mbase + (size_t)r * 96 + ct * 16] = sv;
    }
    s[ct] = accv;
  }

  // softmax over each row
#pragma unroll
  for (int r = 0; r < 4; ++r) {
    float mx = s[0][r];
#pragma unroll
    for (int ct = 1; ct < 6; ++ct) mx = fmaxf(mx, s[ct][r]);
#pragma unroll
    for (int dd = 1; dd < 16; dd <<= 1) mx = fmaxf(mx, __shfl_xor(mx, dd, 64));
    float sum = 0.f;
#pragma unroll
    for (int ct = 0; ct < 6; ++ct) {
      float e = __expf(s[ct][r] - mx);
      s[ct][r] = e;
      sum += e;
    }
#pragma unroll
    for (int dd = 1; dd < 16; dd <<= 1) sum += __shfl_xor(sum, dd, 64);
    float inv = 1.0f / sum;
#pragma unroll
    for (int ct = 0; ct < 6; ++ct)
      Ps[(wave * 16 + quad * 4 + r) * 104 + ct * 16 + m] = __float2bfloat16(s[ct][r] * inv);
  }
  __syncthreads();

  // phase 2: O = P V  (K = 96, 3 k-steps of 32)
  floatx4 o[4] = {};
#pragma unroll
  for (int ks = 0; ks < 3; ++ks) {
    short8 pa = *(const short8*)&Ps[(wave * 16 + m) * 104 + ks * 32 + quad * 8];
#pragma unroll
    for (int ct = 0; ct < 4; ++ct) {
      short8 vv = *(const short8*)&Vt[(ct * 16 + m) * 104 + ks * 32 + quad * 8];
      o[ct] = MFMA16x16x32(pa, vv, o[ct]);
    }
  }
  __hip_bfloat16* cb = ctx + (size_t)b * 96 * 512 + h * 64;
#pragma unroll
  for (int ct = 0; ct < 4; ++ct)
#pragma unroll
    for (int r = 0; r < 4; ++r)
      cb[(size_t)(wave * 16 + quad * 4 + r) * 512 + ct * 16 + m] = __float2bfloat16(o[ct][r]);
}

// ---------------------------------------------------------------- residual + LayerNorm
// wave-per-row (D=512 = 64 lanes x 8 elems), 4 rows/block, shuffle-only reduce.
template <typename RT, typename OT>
__global__ __launch_bounds__(256) void ln_res(
    const __hip_bfloat16* __restrict__ a, const RT* __restrict__ rsd,
    const float* __restrict__ g, const float* __restrict__ be,
    OT* __restrict__ out) {
  const int row = blockIdx.x * 4 + (threadIdx.x >> 6);
  const int lane = threadIdx.x & 63;
  const size_t base = (size_t)row * 512 + lane * 8;
  float x[8], rv[8];
  load8f(a + base, x);
  load8f(rsd + base, rv);
  float s = 0.f, s2 = 0.f;
#pragma unroll
  for (int k = 0; k < 8; ++k) {
    x[k] += rv[k];
    s += x[k];
    s2 += x[k] * x[k];
  }
#pragma unroll
  for (int d = 1; d < 64; d <<= 1) {
    s += __shfl_xor(s, d, 64);
    s2 += __shfl_xor(s2, d, 64);
  }
  const float mean = s * (1.0f / 512.0f);
  const float var = s2 * (1.0f / 512.0f) - mean * mean;
  const float rstd = rsqrtf(var + 1e-5f);
  float gv[8], bv[8], y[8];
  load8f(g + lane * 8, gv);
  load8f(be + lane * 8, bv);
#pragma unroll
  for (int k = 0; k < 8; ++k) y[k] = (x[k] - mean) * rstd * gv[k] + bv[k];
  store8f(out + base, y);
}

// ---------------------------------------------------------------- launch
extern "C" void kernel_launch(void* const* d_in, const int* in_sizes, int n_in,
                              void* d_out, int out_size, void* d_ws, size_t ws_size,
                              hipStream_t stream) {
  (void)in_sizes; (void)n_in; (void)out_size; (void)ws_size;
  typedef const float* cf;
  typedef __hip_bfloat16* bf;
  cf src = (cf)d_in[0];
  cf Wq = (cf)d_in[1];  cf bq = (cf)d_in[2];
  cf Wk = (cf)d_in[3];  cf bk = (cf)d_in[4];
  cf Wv = (cf)d_in[5];  cf bv = (cf)d_in[6];
  cf mat = (cf)d_in[7];
  cf Wo = (cf)d_in[8];  cf bo = (cf)d_in[9];
  cf g1 = (cf)d_in[10]; cf be1 = (cf)d_in[11];
  cf W1 = (cf)d_in[12]; cf b1 = (cf)d_in[13];
  cf W2 = (cf)d_in[14]; cf b2 = (cf)d_in[15];
  cf g2 = (cf)d_in[16]; cf be2 = (cf)d_in[17];

  char* ws = (char*)d_ws;
  const size_t SZ = (size_t)24576 * 512 * 2;  // 25,165,824 B
  bf qkv = (bf)(ws);                  // [24576][1536] bf16 = 3*SZ
  bf ctx = (bf)(ws + 3 * SZ);
  bf hb  = (bf)(ws);                  // FFN hidden [24576][2048] = 4*SZ; qkv+ctx dead by then
  bf srcb = (bf)(ws + 4 * SZ);        // dead after qkv-gemm
  bf tmp = (bf)(ws + 4 * SZ);         // wo out -> ln1; later ffn2 out -> ln2
  bf xb  = (bf)(ws + 5 * SZ);         // post-LN1 x
  char* wt = ws + 6 * SZ;
  bf WqkvT = (bf)(wt);                          // [1536][512] bf16
  bf WoT = (bf)(wt + 1572864);
  bf W1T = (bf)(wt + 1572864 + 524288);         // [2048][512]
  bf W2T = (bf)(wt + 1572864 + 524288 + 2097152);  // [512][2048]
  float* bqkv = (float*)(wt + 1572864 + 524288 + 2097152 + 2097152);

  float* yout = (float*)d_out;
  float* scout = (float*)d_out + 12582912;  // scores after y

  cvt_f32_bf16<<<12288, 256, 0, stream>>>((const float4*)src, (ushort*)srcb);
  concat3<<<6, 256, 0, stream>>>(bq, bk, bv, bqkv);

  dim3 tb(32, 8);
  transpose_cvt<<<dim3(16, 16), tb, 0, stream>>>(Wq, WqkvT, 512, 512);
  transpose_cvt<<<dim3(16, 16), tb, 0, stream>>>(Wk, WqkvT + 512 * 512, 512, 512);
  transpose_cvt<<<dim3(16, 16), tb, 0, stream>>>(Wv, WqkvT + 1024 * 512, 512, 512);
  transpose_cvt<<<dim3(16, 16), tb, 0, stream>>>(Wo, WoT, 512, 512);
  transpose_cvt<<<dim3(64, 16), tb, 0, stream>>>(W1, W1T, 512, 2048);
  transpose_cvt<<<dim3(16, 64), tb, 0, stream>>>(W2, W2T, 2048, 512);

  // 128x128-tile m97-style GEMMs; tiles_x = N/128, grid = (M/128)*(N/128), all %8==0
  gemm128<<<2304, 256, 0, stream>>>(srcb, WqkvT, bqkv, qkv, 1536, 512, 0, 12);

  attn_fused<<<2048, 384, 0, stream>>>(qkv, mat, scout, ctx);

  gemm128<<<768, 256, 0, stream>>>(ctx, WoT, bo, tmp, 512, 512, 0, 4);
  ln_res<float, __hip_bfloat16><<<6144, 256, 0, stream>>>(tmp, src, g1, be1, xb);
  gemm128<<<3072, 256, 0, stream>>>(xb, W1T, b1, hb, 2048, 512, 1, 16);
  gemm128<<<768, 256, 0, stream>>>(hb, W2T, b2, tmp, 512, 2048, 0, 4);
  ln_res<__hip_bfloat16, float><<<6144, 256, 0, stream>>>(tmp, xb, g2, be2, yout);
}

// Round 10
// 513.043 us; speedup vs baseline: 1.2157x; 1.0454x over previous
//
#include <hip/hip_runtime.h>
#include <hip/hip_bf16.h>
#include <math.h>

typedef __attribute__((ext_vector_type(8))) short short8;
typedef __attribute__((ext_vector_type(4))) float floatx4;

// ---------------------------------------------------------------- helpers
__device__ __forceinline__ void load_lds16(const void* g, void* l) {
  __builtin_amdgcn_global_load_lds(
      (__attribute__((address_space(1))) void*)(g),
      (__attribute__((address_space(3))) void*)(l), 16, 0, 0);
}

#define MFMA16x16x32(a, b, c) __builtin_amdgcn_mfma_f32_16x16x32_bf16((a), (b), (c), 0, 0, 0)

__device__ __forceinline__ float to_f(float x) { return x; }
__device__ __forceinline__ float to_f(__hip_bfloat16 x) { return __bfloat162float(x); }

// vectorized 8-element load/store (G13: never scalar bf16)
__device__ __forceinline__ void load8f(const float* p, float* x) {
  float4 a = *(const float4*)p, b = *(const float4*)(p + 4);
  x[0] = a.x; x[1] = a.y; x[2] = a.z; x[3] = a.w;
  x[4] = b.x; x[5] = b.y; x[6] = b.z; x[7] = b.w;
}
__device__ __forceinline__ void load8f(const __hip_bfloat16* p, float* x) {
  short8 v = *(const short8*)p;
#pragma unroll
  for (int k = 0; k < 8; ++k) {
    ushort u = (ushort)v[k];
    __hip_bfloat16 h;
    *(ushort*)&h = u;
    x[k] = __bfloat162float(h);
  }
}
__device__ __forceinline__ void store8f(float* p, const float* x) {
  *(float4*)p = make_float4(x[0], x[1], x[2], x[3]);
  *(float4*)(p + 4) = make_float4(x[4], x[5], x[6], x[7]);
}
__device__ __forceinline__ void store8f(__hip_bfloat16* p, const float* x) {
  short8 o;
#pragma unroll
  for (int k = 0; k < 8; ++k) {
    __hip_bfloat16 h = __float2bfloat16(x[k]);
    o[k] = *(ushort*)&h;
  }
  *(short8*)p = o;
}

// ---------------------------------------------------------------- fused prep (1 launch replaces 8):
// blocks [0,12288): src f32->bf16; [12288,12294): bias concat;
// [12294,+1024): Wq/Wk/Wv/Wo 512x512 transposes; +1024: W1 (512x2048);
// +1024: W2 (2048x512). All independent input-only transforms; branch is
// block-uniform; early-return branches never reach the barrier.
__global__ __launch_bounds__(256) void prep(
    const float4* __restrict__ src4, ushort* __restrict__ srcb,
    const float* __restrict__ bq, const float* __restrict__ bk,
    const float* __restrict__ bv, float* __restrict__ bqkv,
    const float* __restrict__ Wq, const float* __restrict__ Wk,
    const float* __restrict__ Wv, const float* __restrict__ Wo,
    const float* __restrict__ W1, const float* __restrict__ W2,
    __hip_bfloat16* __restrict__ WqkvT, __hip_bfloat16* __restrict__ WoT,
    __hip_bfloat16* __restrict__ W1T, __hip_bfloat16* __restrict__ W2T) {
  __shared__ __hip_bfloat16 tile[32][33];
  const int bid = blockIdx.x;
  const int tid = threadIdx.x;
  if (bid < 12288) {  // ---- src cvt ----
    int i = bid * 256 + tid;
    float4 v = src4[i];
    ushort4 o;
    __hip_bfloat16 b0 = __float2bfloat16(v.x);
    __hip_bfloat16 b1 = __float2bfloat16(v.y);
    __hip_bfloat16 b2 = __float2bfloat16(v.z);
    __hip_bfloat16 b3 = __float2bfloat16(v.w);
    o.x = *(ushort*)&b0; o.y = *(ushort*)&b1; o.z = *(ushort*)&b2; o.w = *(ushort*)&b3;
    *(ushort4*)(srcb + 4 * i) = o;
    return;
  }
  if (bid < 12294) {  // ---- bias concat ----
    int i = (bid - 12288) * 256 + tid;
    bqkv[i] = i < 512 ? bq[i] : (i < 1024 ? bk[i - 512] : bv[i - 1024]);
    return;
  }
  // ---- weight transposes ----
  const int id = bid - 12294;
  const float* tin;
  __hip_bfloat16* tout;
  int R, C, bx, by;
  if (id < 1024) {  // four 512x512
    const int which = id >> 8, t = id & 255;
    tin = which == 0 ? Wq : which == 1 ? Wk : which == 2 ? Wv : Wo;
    tout = which == 3 ? WoT : WqkvT + which * 512 * 512;
    R = 512; C = 512; bx = (t & 15) * 32; by = (t >> 4) * 32;
  } else if (id < 2048) {  // W1 [512][2048]
    const int t = id - 1024;
    tin = W1; tout = W1T; R = 512; C = 2048;
    bx = (t & 63) * 32; by = (t >> 6) * 32;
  } else {  // W2 [2048][512]
    const int t = id - 2048;
    tin = W2; tout = W2T; R = 2048; C = 512;
    bx = (t & 15) * 32; by = (t >> 4) * 32;
  }
  const int tx = tid & 31, ty = tid >> 5;
  for (int i = ty; i < 32; i += 8)
    tile[i][tx] = __float2bfloat16(tin[(size_t)(by + i) * C + bx + tx]);
  __syncthreads();
  for (int i = ty; i < 32; i += 8) tout[(size_t)(bx + i) * R + by + tx] = tile[tx][i];
}

// ---------------------------------------------------------------- GEMM: C[M,N] = A[M,K] @ BT[N,K]^T + bias, opt GELU
// m97-class structure (r7/r9-verified: ~600 TF FFN1, conflicts=0): 128x128
// tile, BK=64, 4 waves (2M x 2N), acc[4][4] (64 AGPR), single 32 KB LDS
// buffer, 2 barriers/K-tile; overlap from 3 independent blocks/CU.
// LDS swizzle (counter-verified): 16-B chunk c of each 128-B row holds global
// chunk c^(row&7); stage = linear global_load_lds dest + pre-swizzled GLOBAL
// source chunk (l&7)^(l>>3); read chunk' = (quad+4*kk)^(m&7).
// Staged epilogue (r9-verified: WRITE_SIZE exactly ideal, FETCH -32%).
__global__ __launch_bounds__(256, 4) void gemm128(
    const __hip_bfloat16* __restrict__ A,
    const __hip_bfloat16* __restrict__ BT,
    const float* __restrict__ bias,
    __hip_bfloat16* __restrict__ C,
    int N, int K, int act, int tiles_x) {
  __shared__ __align__(16) short8 smv[2048];  // 32 KB
  char* smc = (char*)smv;
  const int tid = threadIdx.x;
  const int wave = tid >> 6, lane = tid & 63;
  const int quad = lane >> 4, m = lane & 15;
  const int wmi = wave >> 1, wni = wave & 1;
  // bijective XCD-chunked swizzle (grid % 8 == 0 for all call sites)
  const int nwg = gridDim.x;
  const int wg = (blockIdx.x & 7) * (nwg >> 3) + (blockIdx.x >> 3);
  const int row0 = (wg / tiles_x) * 128;
  const int col0 = (wg % tiles_x) * 128;
  const int nt = K >> 6;

  // ---- staging (pre-swizzled source chunk; linear LDS dest) ----
  const int colb = (((lane & 7) ^ (lane >> 3)) << 4);
  const int rbase = wave * 8 + (lane >> 3);
  const char* pA[4];
  const char* pB[4];
  char* dA[4];
  char* dB[4];
#pragma unroll
  for (int r = 0; r < 4; ++r) {
    pA[r] = (const char*)(A + (size_t)(row0 + rbase + r * 32) * K) + colb;
    pB[r] = (const char*)(BT + (size_t)(col0 + rbase + r * 32) * K) + colb;
    dA[r] = smc + (r * 4 + wave) * 1024;
    dB[r] = smc + 16384 + (r * 4 + wave) * 1024;
  }

  // ---- fragment read indices (16-B units; typed LDS -> ds_read_b128) ----
  const int rc0 = m * 8 + ((quad)     ^ (m & 7));
  const int rc1 = m * 8 + ((quad + 4) ^ (m & 7));
  const int aB = wmi * 512;         // A rows wmi*64..+63
  const int bB = 1024 + wni * 512;  // B cols wni*64..+63

  floatx4 acc[4][4] = {};

  for (int t = 0; t < nt; ++t) {
#pragma unroll
    for (int r = 0; r < 4; ++r) { load_lds16(pA[r], dA[r]); pA[r] += 128; }
#pragma unroll
    for (int r = 0; r < 4; ++r) { load_lds16(pB[r], dB[r]); pB[r] += 128; }
    __syncthreads();  // compiler drains vmcnt(0) here (m97 behavior)
    short8 aF[4], bF[4];
    // kk0
#pragma unroll
    for (int i = 0; i < 4; ++i) aF[i] = smv[aB + i * 128 + rc0];
#pragma unroll
    for (int j = 0; j < 4; ++j) bF[j] = smv[bB + j * 128 + rc0];
#pragma unroll
    for (int i = 0; i < 4; ++i)
#pragma unroll
      for (int j = 0; j < 4; ++j) acc[i][j] = MFMA16x16x32(aF[i], bF[j], acc[i][j]);
    // kk1
#pragma unroll
    for (int i = 0; i < 4; ++i) aF[i] = smv[aB + i * 128 + rc1];
#pragma unroll
    for (int j = 0; j < 4; ++j) bF[j] = smv[bB + j * 128 + rc1];
#pragma unroll
    for (int i = 0; i < 4; ++i)
#pragma unroll
      for (int j = 0; j < 4; ++j) acc[i][j] = MFMA16x16x32(aF[i], bF[j], acc[i][j]);
    __syncthreads();
  }

  // ---------------- epilogue: acc -> swizzled bf16 LDS tile -> coalesced stores
  // LDS tile [128 rows][256 B]; byte = rL*256 + ((colL*2) ^ ((rL&15)<<4)).
  // Round-trip exact (swz bits 4-7; chunk-internal bits 0-3 unaffected).
  {
    ushort* se = (ushort*)smv;
#pragma unroll
    for (int j = 0; j < 4; ++j) {
      const int colL = wni * 64 + j * 16 + m;
      const float bj = bias[col0 + colL];
#pragma unroll
      for (int i = 0; i < 4; ++i) {
        const int rowL = wmi * 64 + i * 16 + quad * 4;
#pragma unroll
        for (int r = 0; r < 4; ++r) {
          float v = acc[i][j][r] + bj;
          if (act == 1) {
            // tanh-form GELU (overflow-safe)
            float tt = 0.7978845608f * (v + 0.044715f * v * v * v);
            float e2 = __expf(-2.0f * fabsf(tt));
            float th = (1.0f - e2) / (1.0f + e2);
            th = tt < 0.0f ? -th : th;
            v = 0.5f * v * (1.0f + th);
          }
          const int rL = rowL + r;
          const int byte = rL * 256 + ((colL * 2) ^ ((rL & 15) << 4));
          __hip_bfloat16 bv = __float2bfloat16(v);
          se[byte >> 1] = *(ushort*)&bv;
        }
      }
    }
    __syncthreads();
#pragma unroll
    for (int p = 0; p < 8; ++p) {
      const int rL = p * 16 + (tid >> 4);
      const int c = tid & 15;
      const int byte = rL * 256 + ((c * 16) ^ ((rL & 15) << 4));
      *(short8*)(C + (size_t)(row0 + rL) * N + col0 + c * 8) =
          *(const short8*)(smc + byte);
    }
  }
}

// ---------------------------------------------------------------- fused attention per (b,h)
// qkv fused: row stride 1536; q at col h*64, k at 512+h*64, v at 1024+h*64.
__global__ __launch_bounds__(384) void attn_fused(
    const __hip_bfloat16* __restrict__ qkv,
    const float* __restrict__ mat,
    float* __restrict__ scores,
    __hip_bfloat16* __restrict__ ctx) {
  __shared__ __align__(16) __hip_bfloat16 Ks[96 * 72];   // [l_k][d], pad 64->72
  __shared__ __align__(16) __hip_bfloat16 Vt[64 * 104];  // [d][l_k], pad 96->104
  __shared__ __align__(16) __hip_bfloat16 Ps[96 * 104];  // [l_q][l_k], pad 96->104
  const int bh = blockIdx.x;
  const int b = bh >> 3, h = bh & 7;
  const __hip_bfloat16* qb = qkv + (size_t)b * 96 * 1536 + h * 64;
  const __hip_bfloat16* kb = qb + 512;
  const __hip_bfloat16* vb = qb + 1024;
  const int tid = threadIdx.x;

  // stage K [96][64] -> Ks, 16B chunks
  for (int c = tid; c < 768; c += 384) {
    int row = c >> 3, c8 = (c & 7) * 8;
    *(short8*)&Ks[row * 72 + c8] = *(const short8*)(kb + (size_t)row * 1536 + c8);
  }
  // stage V transposed
  {
    int d = tid & 63;
    for (int l = tid >> 6; l < 96; l += 6) Vt[d * 104 + l] = vb[(size_t)l * 1536 + d];
  }
  __syncthreads();

  const int wave = tid >> 6, lane = tid & 63;
  const int quad = lane >> 4, m = lane & 15;

  // phase 1: S = Q K^T (16 rows per wave, N=96, K=64)
  short8 a0 = *(const short8*)(qb + (size_t)(wave * 16 + m) * 1536 + quad * 8);
  short8 a1 = *(const short8*)(qb + (size_t)(wave * 16 + m) * 1536 + 32 + quad * 8);
  floatx4 s[6];
  const size_t mbase = ((size_t)bh * 96 + wave * 16 + quad * 4) * 96 + m;
#pragma unroll
  for (int ct = 0; ct < 6; ++ct) {
    short8 b0 = *(const short8*)&Ks[(ct * 16 + m) * 72 + quad * 8];
    short8 b1 = *(const short8*)&Ks[(ct * 16 + m) * 72 + 32 + quad * 8];
    floatx4 accv = {};
    accv = MFMA16x16x32(a0, b0, accv);
    accv = MFMA16x16x32(a1, b1, accv);
#pragma unroll
    for (int r = 0; r < 4; ++r) {
      float sv = accv[r] * 0.125f * mat[mbase + (size_t)r * 96 + ct * 16];
      accv[r] = sv;
      scores[mbase + (size_t)r * 96 + ct * 16] = sv;
    }
    s[ct] = accv;
  }

  // softmax over each row
#pragma unroll
  for (int r = 0; r < 4; ++r) {
    float mx = s[0][r];
#pragma unroll
    for (int ct = 1; ct < 6; ++ct) mx = fmaxf(mx, s[ct][r]);
#pragma unroll
    for (int dd = 1; dd < 16; dd <<= 1) mx = fmaxf(mx, __shfl_xor(mx, dd, 64));
    float sum = 0.f;
#pragma unroll
    for (int ct = 0; ct < 6; ++ct) {
      float e = __expf(s[ct][r] - mx);
      s[ct][r] = e;
      sum += e;
    }
#pragma unroll
    for (int dd = 1; dd < 16; dd <<= 1) sum += __shfl_xor(sum, dd, 64);
    float inv = 1.0f / sum;
#pragma unroll
    for (int ct = 0; ct < 6; ++ct)
      Ps[(wave * 16 + quad * 4 + r) * 104 + ct * 16 + m] = __float2bfloat16(s[ct][r] * inv);
  }
  __syncthreads();

  // phase 2: O = P V  (K = 96, 3 k-steps of 32)
  floatx4 o[4] = {};
#pragma unroll
  for (int ks = 0; ks < 3; ++ks) {
    short8 pa = *(const short8*)&Ps[(wave * 16 + m) * 104 + ks * 32 + quad * 8];
#pragma unroll
    for (int ct = 0; ct < 4; ++ct) {
      short8 vv = *(const short8*)&Vt[(ct * 16 + m) * 104 + ks * 32 + quad * 8];
      o[ct] = MFMA16x16x32(pa, vv, o[ct]);
    }
  }
  __hip_bfloat16* cb = ctx + (size_t)b * 96 * 512 + h * 64;
#pragma unroll
  for (int ct = 0; ct < 4; ++ct)
#pragma unroll
    for (int r = 0; r < 4; ++r)
      cb[(size_t)(wave * 16 + quad * 4 + r) * 512 + ct * 16 + m] = __float2bfloat16(o[ct][r]);
}

// ---------------------------------------------------------------- residual + LayerNorm
// wave-per-row (D=512 = 64 lanes x 8 elems), 4 rows/block, shuffle-only reduce.
template <typename RT, typename OT>
__global__ __launch_bounds__(256) void ln_res(
    const __hip_bfloat16* __restrict__ a, const RT* __restrict__ rsd,
    const float* __restrict__ g, const float* __restrict__ be,
    OT* __restrict__ out) {
  const int row = blockIdx.x * 4 + (threadIdx.x >> 6);
  const int lane = threadIdx.x & 63;
  const size_t base = (size_t)row * 512 + lane * 8;
  float x[8], rv[8];
  load8f(a + base, x);
  load8f(rsd + base, rv);
  float s = 0.f, s2 = 0.f;
#pragma unroll
  for (int k = 0; k < 8; ++k) {
    x[k] += rv[k];
    s += x[k];
    s2 += x[k] * x[k];
  }
#pragma unroll
  for (int d = 1; d < 64; d <<= 1) {
    s += __shfl_xor(s, d, 64);
    s2 += __shfl_xor(s2, d, 64);
  }
  const float mean = s * (1.0f / 512.0f);
  const float var = s2 * (1.0f / 512.0f) - mean * mean;
  const float rstd = rsqrtf(var + 1e-5f);
  float gv[8], bv[8], y[8];
  load8f(g + lane * 8, gv);
  load8f(be + lane * 8, bv);
#pragma unroll
  for (int k = 0; k < 8; ++k) y[k] = (x[k] - mean) * rstd * gv[k] + bv[k];
  store8f(out + base, y);
}

// ---------------------------------------------------------------- launch
extern "C" void kernel_launch(void* const* d_in, const int* in_sizes, int n_in,
                              void* d_out, int out_size, void* d_ws, size_t ws_size,
                              hipStream_t stream) {
  (void)in_sizes; (void)n_in; (void)out_size; (void)ws_size;
  typedef const float* cf;
  typedef __hip_bfloat16* bf;
  cf src = (cf)d_in[0];
  cf Wq = (cf)d_in[1];  cf bq = (cf)d_in[2];
  cf Wk = (cf)d_in[3];  cf bk = (cf)d_in[4];
  cf Wv = (cf)d_in[5];  cf bv = (cf)d_in[6];
  cf mat = (cf)d_in[7];
  cf Wo = (cf)d_in[8];  cf bo = (cf)d_in[9];
  cf g1 = (cf)d_in[10]; cf be1 = (cf)d_in[11];
  cf W1 = (cf)d_in[12]; cf b1 = (cf)d_in[13];
  cf W2 = (cf)d_in[14]; cf b2 = (cf)d_in[15];
  cf g2 = (cf)d_in[16]; cf be2 = (cf)d_in[17];

  char* ws = (char*)d_ws;
  const size_t SZ = (size_t)24576 * 512 * 2;  // 25,165,824 B
  bf qkv = (bf)(ws);                  // [24576][1536] bf16 = 3*SZ
  bf ctx = (bf)(ws + 3 * SZ);
  bf hb  = (bf)(ws);                  // FFN hidden [24576][2048] = 4*SZ; qkv+ctx dead by then
  bf srcb = (bf)(ws + 4 * SZ);        // dead after qkv-gemm
  bf tmp = (bf)(ws + 4 * SZ);         // wo out -> ln1; later ffn2 out -> ln2
  bf xb  = (bf)(ws + 5 * SZ);         // post-LN1 x
  char* wt = ws + 6 * SZ;
  bf WqkvT = (bf)(wt);                          // [1536][512] bf16
  bf WoT = (bf)(wt + 1572864);
  bf W1T = (bf)(wt + 1572864 + 524288);         // [2048][512]
  bf W2T = (bf)(wt + 1572864 + 524288 + 2097152);  // [512][2048]
  float* bqkv = (float*)(wt + 1572864 + 524288 + 2097152 + 2097152);

  float* yout = (float*)d_out;
  float* scout = (float*)d_out + 12582912;  // scores after y

  // fused prep: 12288 cvt + 6 concat + 1024 (4x512x512) + 1024 (W1) + 1024 (W2)
  prep<<<15366, 256, 0, stream>>>((const float4*)src, (ushort*)srcb,
                                  bq, bk, bv, bqkv,
                                  Wq, Wk, Wv, Wo, W1, W2,
                                  WqkvT, WoT, W1T, W2T);

  // 128x128-tile m97-style GEMMs; tiles_x = N/128, grid = (M/128)*(N/128), all %8==0
  gemm128<<<2304, 256, 0, stream>>>(srcb, WqkvT, bqkv, qkv, 1536, 512, 0, 12);

  attn_fused<<<2048, 384, 0, stream>>>(qkv, mat, scout, ctx);

  gemm128<<<768, 256, 0, stream>>>(ctx, WoT, bo, tmp, 512, 512, 0, 4);
  ln_res<float, __hip_bfloat16><<<6144, 256, 0, stream>>>(tmp, src, g1, be1, xb);
  gemm128<<<3072, 256, 0, stream>>>(xb, W1T, b1, hb, 2048, 512, 1, 16);
  gemm128<<<768, 256, 0, stream>>>(hb, W2T, b2, tmp, 512, 2048, 0, 4);
  ln_res<__hip_bfloat16, float><<<6144, 256, 0, stream>>>(tmp, xb, g2, be2, yout);
}

// Round 11
// 483.523 us; speedup vs baseline: 1.2899x; 1.0611x over previous
//
#include <hip/hip_runtime.h>
#include <hip/hip_bf16.h>
#include <math.h>

typedef __attribute__((ext_vector_type(8))) short short8;
typedef __attribute__((ext_vector_type(4))) float floatx4;

// ---------------------------------------------------------------- helpers
__device__ __forceinline__ void load_lds16(const void* g, void* l) {
  __builtin_amdgcn_global_load_lds(
      (__attribute__((address_space(1))) void*)(g),
      (__attribute__((address_space(3))) void*)(l), 16, 0, 0);
}

#define MFMA16x16x32(a, b, c) __builtin_amdgcn_mfma_f32_16x16x32_bf16((a), (b), (c), 0, 0, 0)

__device__ __forceinline__ float to_f(float x) { return x; }
__device__ __forceinline__ float to_f(__hip_bfloat16 x) { return __bfloat162float(x); }

// vectorized 8-element load/store (G13: never scalar bf16)
__device__ __forceinline__ void load8f(const float* p, float* x) {
  float4 a = *(const float4*)p, b = *(const float4*)(p + 4);
  x[0] = a.x; x[1] = a.y; x[2] = a.z; x[3] = a.w;
  x[4] = b.x; x[5] = b.y; x[6] = b.z; x[7] = b.w;
}
__device__ __forceinline__ void load8f(const __hip_bfloat16* p, float* x) {
  short8 v = *(const short8*)p;
#pragma unroll
  for (int k = 0; k < 8; ++k) {
    ushort u = (ushort)v[k];
    __hip_bfloat16 h;
    *(ushort*)&h = u;
    x[k] = __bfloat162float(h);
  }
}
__device__ __forceinline__ void store8f(float* p, const float* x) {
  *(float4*)p = make_float4(x[0], x[1], x[2], x[3]);
  *(float4*)(p + 4) = make_float4(x[4], x[5], x[6], x[7]);
}
__device__ __forceinline__ void store8f(__hip_bfloat16* p, const float* x) {
  short8 o;
#pragma unroll
  for (int k = 0; k < 8; ++k) {
    __hip_bfloat16 h = __float2bfloat16(x[k]);
    o[k] = *(ushort*)&h;
  }
  *(short8*)p = o;
}

// ---------------------------------------------------------------- fused prep (1 launch replaces 8)
__global__ __launch_bounds__(256) void prep(
    const float4* __restrict__ src4, ushort* __restrict__ srcb,
    const float* __restrict__ bq, const float* __restrict__ bk,
    const float* __restrict__ bv, float* __restrict__ bqkv,
    const float* __restrict__ Wq, const float* __restrict__ Wk,
    const float* __restrict__ Wv, const float* __restrict__ Wo,
    const float* __restrict__ W1, const float* __restrict__ W2,
    __hip_bfloat16* __restrict__ WqkvT, __hip_bfloat16* __restrict__ WoT,
    __hip_bfloat16* __restrict__ W1T, __hip_bfloat16* __restrict__ W2T) {
  __shared__ __hip_bfloat16 tile[32][33];
  const int bid = blockIdx.x;
  const int tid = threadIdx.x;
  if (bid < 12288) {  // ---- src cvt ----
    int i = bid * 256 + tid;
    float4 v = src4[i];
    ushort4 o;
    __hip_bfloat16 b0 = __float2bfloat16(v.x);
    __hip_bfloat16 b1 = __float2bfloat16(v.y);
    __hip_bfloat16 b2 = __float2bfloat16(v.z);
    __hip_bfloat16 b3 = __float2bfloat16(v.w);
    o.x = *(ushort*)&b0; o.y = *(ushort*)&b1; o.z = *(ushort*)&b2; o.w = *(ushort*)&b3;
    *(ushort4*)(srcb + 4 * i) = o;
    return;
  }
  if (bid < 12294) {  // ---- bias concat ----
    int i = (bid - 12288) * 256 + tid;
    bqkv[i] = i < 512 ? bq[i] : (i < 1024 ? bk[i - 512] : bv[i - 1024]);
    return;
  }
  // ---- weight transposes ----
  const int id = bid - 12294;
  const float* tin;
  __hip_bfloat16* tout;
  int R, C, bx, by;
  if (id < 1024) {  // four 512x512
    const int which = id >> 8, t = id & 255;
    tin = which == 0 ? Wq : which == 1 ? Wk : which == 2 ? Wv : Wo;
    tout = which == 3 ? WoT : WqkvT + which * 512 * 512;
    R = 512; C = 512; bx = (t & 15) * 32; by = (t >> 4) * 32;
  } else if (id < 2048) {  // W1 [512][2048]
    const int t = id - 1024;
    tin = W1; tout = W1T; R = 512; C = 2048;
    bx = (t & 63) * 32; by = (t >> 6) * 32;
  } else {  // W2 [2048][512]
    const int t = id - 2048;
    tin = W2; tout = W2T; R = 2048; C = 512;
    bx = (t & 15) * 32; by = (t >> 4) * 32;
  }
  const int tx = tid & 31, ty = tid >> 5;
  for (int i = ty; i < 32; i += 8)
    tile[i][tx] = __float2bfloat16(tin[(size_t)(by + i) * C + bx + tx]);
  __syncthreads();
  for (int i = ty; i < 32; i += 8) tout[(size_t)(bx + i) * R + by + tx] = tile[tx][i];
}

// ---------------------------------------------------------------- GEMM: C[M,N] = A[M,K] @ BT[N,K]^T + bias, opt GELU
// m97-class structure (r7/r9-verified: ~600 TF FFN1, conflicts=0): 128x128
// tile, BK=64, 4 waves (2M x 2N), acc[4][4] (64 AGPR), single 32 KB LDS
// buffer, 2 barriers/K-tile; overlap from 3-4 independent blocks/CU.
// LDS swizzle (counter-verified): 16-B chunk c of each 128-B row holds global
// chunk c^(row&7); stage = linear global_load_lds dest + pre-swizzled GLOBAL
// source chunk (l&7)^(l>>3); read chunk' = (quad+4*kk)^(m&7).
// Staged epilogue (r9-verified: WRITE_SIZE exactly ideal, FETCH -32%).
// r11: GELU tanh-form uses v_rcp_f32 instead of IEEE division (~12 instr -> 1)
// -- r10 showed VALUBusy 65% on act=1 dispatches, epilogue-VALU-bound.
__global__ __launch_bounds__(256, 4) void gemm128(
    const __hip_bfloat16* __restrict__ A,
    const __hip_bfloat16* __restrict__ BT,
    const float* __restrict__ bias,
    __hip_bfloat16* __restrict__ C,
    int N, int K, int act, int tiles_x) {
  __shared__ __align__(16) short8 smv[2048];  // 32 KB
  char* smc = (char*)smv;
  const int tid = threadIdx.x;
  const int wave = tid >> 6, lane = tid & 63;
  const int quad = lane >> 4, m = lane & 15;
  const int wmi = wave >> 1, wni = wave & 1;
  // bijective XCD-chunked swizzle (grid % 8 == 0 for all call sites)
  const int nwg = gridDim.x;
  const int wg = (blockIdx.x & 7) * (nwg >> 3) + (blockIdx.x >> 3);
  const int row0 = (wg / tiles_x) * 128;
  const int col0 = (wg % tiles_x) * 128;
  const int nt = K >> 6;

  // ---- staging (pre-swizzled source chunk; linear LDS dest) ----
  const int colb = (((lane & 7) ^ (lane >> 3)) << 4);
  const int rbase = wave * 8 + (lane >> 3);
  const char* pA[4];
  const char* pB[4];
  char* dA[4];
  char* dB[4];
#pragma unroll
  for (int r = 0; r < 4; ++r) {
    pA[r] = (const char*)(A + (size_t)(row0 + rbase + r * 32) * K) + colb;
    pB[r] = (const char*)(BT + (size_t)(col0 + rbase + r * 32) * K) + colb;
    dA[r] = smc + (r * 4 + wave) * 1024;
    dB[r] = smc + 16384 + (r * 4 + wave) * 1024;
  }

  // ---- fragment read indices (16-B units; typed LDS -> ds_read_b128) ----
  const int rc0 = m * 8 + ((quad)     ^ (m & 7));
  const int rc1 = m * 8 + ((quad + 4) ^ (m & 7));
  const int aB = wmi * 512;         // A rows wmi*64..+63
  const int bB = 1024 + wni * 512;  // B cols wni*64..+63

  floatx4 acc[4][4] = {};

  for (int t = 0; t < nt; ++t) {
#pragma unroll
    for (int r = 0; r < 4; ++r) { load_lds16(pA[r], dA[r]); pA[r] += 128; }
#pragma unroll
    for (int r = 0; r < 4; ++r) { load_lds16(pB[r], dB[r]); pB[r] += 128; }
    __syncthreads();  // compiler drains vmcnt(0) here (m97 behavior)
    short8 aF[4], bF[4];
    // kk0
#pragma unroll
    for (int i = 0; i < 4; ++i) aF[i] = smv[aB + i * 128 + rc0];
#pragma unroll
    for (int j = 0; j < 4; ++j) bF[j] = smv[bB + j * 128 + rc0];
#pragma unroll
    for (int i = 0; i < 4; ++i)
#pragma unroll
      for (int j = 0; j < 4; ++j) acc[i][j] = MFMA16x16x32(aF[i], bF[j], acc[i][j]);
    // kk1
#pragma unroll
    for (int i = 0; i < 4; ++i) aF[i] = smv[aB + i * 128 + rc1];
#pragma unroll
    for (int j = 0; j < 4; ++j) bF[j] = smv[bB + j * 128 + rc1];
#pragma unroll
    for (int i = 0; i < 4; ++i)
#pragma unroll
      for (int j = 0; j < 4; ++j) acc[i][j] = MFMA16x16x32(aF[i], bF[j], acc[i][j]);
    __syncthreads();
  }

  // ---------------- epilogue: acc -> swizzled bf16 LDS tile -> coalesced stores
  {
    ushort* se = (ushort*)smv;
#pragma unroll
    for (int j = 0; j < 4; ++j) {
      const int colL = wni * 64 + j * 16 + m;
      const float bj = bias[col0 + colL];
#pragma unroll
      for (int i = 0; i < 4; ++i) {
        const int rowL = wmi * 64 + i * 16 + quad * 4;
#pragma unroll
        for (int r = 0; r < 4; ++r) {
          float v = acc[i][j][r] + bj;
          if (act == 1) {
            // tanh-form GELU, rcp-based (overflow-safe)
            float tt = 0.7978845608f * (v + 0.044715f * v * v * v);
            float e2 = __expf(-2.0f * fabsf(tt));
            float th = (1.0f - e2) * __builtin_amdgcn_rcpf(1.0f + e2);
            th = tt < 0.0f ? -th : th;
            v = 0.5f * v * (1.0f + th);
          }
          const int rL = rowL + r;
          const int byte = rL * 256 + ((colL * 2) ^ ((rL & 15) << 4));
          __hip_bfloat16 bv = __float2bfloat16(v);
          se[byte >> 1] = *(ushort*)&bv;
        }
      }
    }
    __syncthreads();
#pragma unroll
    for (int p = 0; p < 8; ++p) {
      const int rL = p * 16 + (tid >> 4);
      const int c = tid & 15;
      const int byte = rL * 256 + ((c * 16) ^ ((rL & 15) << 4));
      *(short8*)(C + (size_t)(row0 + rL) * N + col0 + c * 8) =
          *(const short8*)(smc + byte);
    }
  }
}

// ---------------------------------------------------------------- fused attention per (b,h)
// qkv fused: row stride 1536; q at col h*64, k at 512+h*64, v at 1024+h*64.
// r11: V staging via short8 global loads (16 scalar loads -> 2 vector);
// ctx output staged through Ks-region LDS (dead after softmax barrier) ->
// 16-B contiguous global stores (2x sector efficiency on 25 MB).
__global__ __launch_bounds__(384) void attn_fused(
    const __hip_bfloat16* __restrict__ qkv,
    const float* __restrict__ mat,
    float* __restrict__ scores,
    __hip_bfloat16* __restrict__ ctx) {
  __shared__ __align__(16) __hip_bfloat16 Ks[96 * 72];   // [l_k][d], pad 64->72; reused for ctx staging
  __shared__ __align__(16) __hip_bfloat16 Vt[64 * 104];  // [d][l_k], pad 96->104
  __shared__ __align__(16) __hip_bfloat16 Ps[96 * 104];  // [l_q][l_k], pad 96->104
  const int bh = blockIdx.x;
  const int b = bh >> 3, h = bh & 7;
  const __hip_bfloat16* qb = qkv + (size_t)b * 96 * 1536 + h * 64;
  const __hip_bfloat16* kb = qb + 512;
  const __hip_bfloat16* vb = qb + 1024;
  const int tid = threadIdx.x;

  // stage K [96][64] -> Ks, 16B chunks
  for (int c = tid; c < 768; c += 384) {
    int row = c >> 3, c8 = (c & 7) * 8;
    *(short8*)&Ks[row * 72 + c8] = *(const short8*)(kb + (size_t)row * 1536 + c8);
  }
  // stage V transposed: vectorized global read (16B), scalar LDS scatter
  for (int c = tid; c < 768; c += 384) {
    int l = c >> 3, c8 = (c & 7) * 8;
    short8 v = *(const short8*)(vb + (size_t)l * 1536 + c8);
#pragma unroll
    for (int k = 0; k < 8; ++k) ((ushort*)Vt)[(c8 + k) * 104 + l] = (ushort)v[k];
  }
  __syncthreads();

  const int wave = tid >> 6, lane = tid & 63;
  const int quad = lane >> 4, m = lane & 15;

  // phase 1: S = Q K^T (16 rows per wave, N=96, K=64)
  short8 a0 = *(const short8*)(qb + (size_t)(wave * 16 + m) * 1536 + quad * 8);
  short8 a1 = *(const short8*)(qb + (size_t)(wave * 16 + m) * 1536 + 32 + quad * 8);
  floatx4 s[6];
  const size_t mbase = ((size_t)bh * 96 + wave * 16 + quad * 4) * 96 + m;
#pragma unroll
  for (int ct = 0; ct < 6; ++ct) {
    short8 b0 = *(const short8*)&Ks[(ct * 16 + m) * 72 + quad * 8];
    short8 b1 = *(const short8*)&Ks[(ct * 16 + m) * 72 + 32 + quad * 8];
    floatx4 accv = {};
    accv = MFMA16x16x32(a0, b0, accv);
    accv = MFMA16x16x32(a1, b1, accv);
#pragma unroll
    for (int r = 0; r < 4; ++r) {
      float sv = accv[r] * 0.125f * mat[mbase + (size_t)r * 96 + ct * 16];
      accv[r] = sv;
      scores[mbase + (size_t)r * 96 + ct * 16] = sv;
    }
    s[ct] = accv;
  }

  // softmax over each row
#pragma unroll
  for (int r = 0; r < 4; ++r) {
    float mx = s[0][r];
#pragma unroll
    for (int ct = 1; ct < 6; ++ct) mx = fmaxf(mx, s[ct][r]);
#pragma unroll
    for (int dd = 1; dd < 16; dd <<= 1) mx = fmaxf(mx, __shfl_xor(mx, dd, 64));
    float sum = 0.f;
#pragma unroll
    for (int ct = 0; ct < 6; ++ct) {
      float e = __expf(s[ct][r] - mx);
      s[ct][r] = e;
      sum += e;
    }
#pragma unroll
    for (int dd = 1; dd < 16; dd <<= 1) sum += __shfl_xor(sum, dd, 64);
    float inv = 1.0f / sum;
#pragma unroll
    for (int ct = 0; ct < 6; ++ct)
      Ps[(wave * 16 + quad * 4 + r) * 104 + ct * 16 + m] = __float2bfloat16(s[ct][r] * inv);
  }
  __syncthreads();  // after this barrier Ks is dead (phase-1 reads all done)

  // phase 2: O = P V  (K = 96, 3 k-steps of 32)
  floatx4 o[4] = {};
#pragma unroll
  for (int ks = 0; ks < 3; ++ks) {
    short8 pa = *(const short8*)&Ps[(wave * 16 + m) * 104 + ks * 32 + quad * 8];
#pragma unroll
    for (int ct = 0; ct < 4; ++ct) {
      short8 vv = *(const short8*)&Vt[(ct * 16 + m) * 104 + ks * 32 + quad * 8];
      o[ct] = MFMA16x16x32(pa, vv, o[ct]);
    }
  }
  // stage O into Ks region [96][72], then coalesced 16-B stores
#pragma unroll
  for (int ct = 0; ct < 4; ++ct)
#pragma unroll
    for (int r = 0; r < 4; ++r)
      Ks[(wave * 16 + quad * 4 + r) * 72 + ct * 16 + m] = __float2bfloat16(o[ct][r]);
  __syncthreads();
  {
    __hip_bfloat16* cb = ctx + (size_t)b * 96 * 512 + h * 64;
    for (int c = tid; c < 768; c += 384) {
      int row = c >> 3, c8 = (c & 7) * 8;
      *(short8*)(cb + (size_t)row * 512 + c8) = *(const short8*)&Ks[row * 72 + c8];
    }
  }
}

// ---------------------------------------------------------------- residual + LayerNorm
// wave-per-row (D=512 = 64 lanes x 8 elems), 4 rows/block, shuffle-only reduce.
template <typename RT, typename OT>
__global__ __launch_bounds__(256) void ln_res(
    const __hip_bfloat16* __restrict__ a, const RT* __restrict__ rsd,
    const float* __restrict__ g, const float* __restrict__ be,
    OT* __restrict__ out) {
  const int row = blockIdx.x * 4 + (threadIdx.x >> 6);
  const int lane = threadIdx.x & 63;
  const size_t base = (size_t)row * 512 + lane * 8;
  float x[8], rv[8];
  load8f(a + base, x);
  load8f(rsd + base, rv);
  float s = 0.f, s2 = 0.f;
#pragma unroll
  for (int k = 0; k < 8; ++k) {
    x[k] += rv[k];
    s += x[k];
    s2 += x[k] * x[k];
  }
#pragma unroll
  for (int d = 1; d < 64; d <<= 1) {
    s += __shfl_xor(s, d, 64);
    s2 += __shfl_xor(s2, d, 64);
  }
  const float mean = s * (1.0f / 512.0f);
  const float var = s2 * (1.0f / 512.0f) - mean * mean;
  const float rstd = rsqrtf(var + 1e-5f);
  float gv[8], bv[8], y[8];
  load8f(g + lane * 8, gv);
  load8f(be + lane * 8, bv);
#pragma unroll
  for (int k = 0; k < 8; ++k) y[k] = (x[k] - mean) * rstd * gv[k] + bv[k];
  store8f(out + base, y);
}

// ---------------------------------------------------------------- launch
extern "C" void kernel_launch(void* const* d_in, const int* in_sizes, int n_in,
                              void* d_out, int out_size, void* d_ws, size_t ws_size,
                              hipStream_t stream) {
  (void)in_sizes; (void)n_in; (void)out_size; (void)ws_size;
  typedef const float* cf;
  typedef __hip_bfloat16* bf;
  cf src = (cf)d_in[0];
  cf Wq = (cf)d_in[1];  cf bq = (cf)d_in[2];
  cf Wk = (cf)d_in[3];  cf bk = (cf)d_in[4];
  cf Wv = (cf)d_in[5];  cf bv = (cf)d_in[6];
  cf mat = (cf)d_in[7];
  cf Wo = (cf)d_in[8];  cf bo = (cf)d_in[9];
  cf g1 = (cf)d_in[10]; cf be1 = (cf)d_in[11];
  cf W1 = (cf)d_in[12]; cf b1 = (cf)d_in[13];
  cf W2 = (cf)d_in[14]; cf b2 = (cf)d_in[15];
  cf g2 = (cf)d_in[16]; cf be2 = (cf)d_in[17];

  char* ws = (char*)d_ws;
  const size_t SZ = (size_t)24576 * 512 * 2;  // 25,165,824 B
  bf qkv = (bf)(ws);                  // [24576][1536] bf16 = 3*SZ
  bf ctx = (bf)(ws + 3 * SZ);
  bf hb  = (bf)(ws);                  // FFN hidden [24576][2048] = 4*SZ; qkv+ctx dead by then
  bf srcb = (bf)(ws + 4 * SZ);        // dead after qkv-gemm
  bf tmp = (bf)(ws + 4 * SZ);         // wo out -> ln1; later ffn2 out -> ln2
  bf xb  = (bf)(ws + 5 * SZ);         // post-LN1 x
  char* wt = ws + 6 * SZ;
  bf WqkvT = (bf)(wt);                          // [1536][512] bf16
  bf WoT = (bf)(wt + 1572864);
  bf W1T = (bf)(wt + 1572864 + 524288);         // [2048][512]
  bf W2T = (bf)(wt + 1572864 + 524288 + 2097152);  // [512][2048]
  float* bqkv = (float*)(wt + 1572864 + 524288 + 2097152 + 2097152);

  float* yout = (float*)d_out;
  float* scout = (float*)d_out + 12582912;  // scores after y

  // fused prep: 12288 cvt + 6 concat + 1024 (4x512x512) + 1024 (W1) + 1024 (W2)
  prep<<<15366, 256, 0, stream>>>((const float4*)src, (ushort*)srcb,
                                  bq, bk, bv, bqkv,
                                  Wq, Wk, Wv, Wo, W1, W2,
                                  WqkvT, WoT, W1T, W2T);

  // 128x128-tile m97-style GEMMs; tiles_x = N/128, grid = (M/128)*(N/128), all %8==0
  gemm128<<<2304, 256, 0, stream>>>(srcb, WqkvT, bqkv, qkv, 1536, 512, 0, 12);

  attn_fused<<<2048, 384, 0, stream>>>(qkv, mat, scout, ctx);

  gemm128<<<768, 256, 0, stream>>>(ctx, WoT, bo, tmp, 512, 512, 0, 4);
  ln_res<float, __hip_bfloat16><<<6144, 256, 0, stream>>>(tmp, src, g1, be1, xb);
  gemm128<<<3072, 256, 0, stream>>>(xb, W1T, b1, hb, 2048, 512, 1, 16);
  gemm128<<<768, 256, 0, stream>>>(hb, W2T, b2, tmp, 512, 2048, 0, 4);
  ln_res<__hip_bfloat16, float><<<6144, 256, 0, stream>>>(tmp, xb, g2, be2, yout);
}